// Round 11
// baseline (710.397 us; speedup 1.0000x reference)
//
#include <hip/hip_runtime.h>
#include <math.h>

#define LSEQ 4096
#define DIMC 256
#define DI   512
#define NCH  64     // chunks over L
#define CHL  64     // chunk length

typedef short short8 __attribute__((ext_vector_type(8)));
typedef float f32x4 __attribute__((ext_vector_type(4)));

__device__ __forceinline__ float sp_f(float v){ return fmaxf(v,0.f) + log1pf(__expf(-fabsf(v))); }
__device__ __forceinline__ float silu_f(float v){ return v/(1.f+__expf(-v)); }
__device__ __forceinline__ unsigned short f2bf(float f){
  unsigned u = __builtin_bit_cast(unsigned, f);
  unsigned r = (u + 0x7FFFu + ((u>>16)&1u)) >> 16;
  return (unsigned short)r;
}
__device__ __forceinline__ float bf2f(unsigned short us){
  unsigned u = ((unsigned)us)<<16;
  return __builtin_bit_cast(float, u);
}

// ---------------- LayerNorm: x (B,C,L) -> h_bf (B*L, C) bf16 -------------------------
__global__ __launch_bounds__(64) void ln_kernel(const float* __restrict__ x,
                                                const float* __restrict__ w,
                                                const float* __restrict__ bias,
                                                unsigned short* __restrict__ hb){
  int row = blockIdx.x;            // b*L + l
  int b = row >> 12, l = row & 4095;
  int i = threadIdx.x;             // 0..63
  const float* xb = x + (size_t)b*DIMC*LSEQ + l;
  float v[4]; float s=0.f, sq=0.f;
  #pragma unroll
  for(int j=0;j<4;j++){ float t = xb[(size_t)(j*64+i)*LSEQ]; v[j]=t; s+=t; sq+=t*t; }
  #pragma unroll
  for(int o=1;o<64;o<<=1){ s += __shfl_xor(s,o); sq += __shfl_xor(sq,o); }
  float mu = s*(1.f/256.f);
  float var = sq*(1.f/256.f) - mu*mu;
  float rs = rsqrtf(var + 1e-5f);
  unsigned short* hr = hb + (size_t)row*DIMC;
  #pragma unroll
  for(int j=0;j<4;j++){ int c=j*64+i; hr[c] = f2bf((v[j]-mu)*rs*w[c] + bias[c]); }
}

// ---------------- generic bf16 copy of weights ---------------------------------------
__global__ __launch_bounds__(256) void cvt_bf(const float* __restrict__ src,
                                              unsigned short* __restrict__ dst, int n){
  int i = blockIdx.x*256 + threadIdx.x;
  if(i < n) dst[i] = f2bf(src[i]);
}

// ---------------- W_dt[dep][n][k] = sum_j dtw[dep][n][j] * xpw[dep][j][k] ------------
__global__ __launch_bounds__(256) void wdt_kernel(const float* __restrict__ dtw,
                                                  const float* __restrict__ xpw,
                                                  unsigned short* __restrict__ wdt){
  int idx = blockIdx.x*256 + threadIdx.x;   // 0..524287
  int dep = idx >> 18;
  int r = idx & 262143;
  int n = r >> 9, k = r & 511;
  const float* dw = dtw + (size_t)dep*512*16 + n*16;
  const float* xp = xpw + (size_t)dep*48*512 + k;
  float acc = 0.f;
  #pragma unroll
  for(int j=0;j<16;j++) acc += dw[j] * xp[(size_t)j*512];
  wdt[idx] = f2bf(acc);
}

// ---------------- all-global bf16 MFMA GEMM: D[n][m] = W[n,:]·A[m,:] -----------------
template<int FM,int FN,int WM,int WN,int EPI,int WF,int WB>
__global__ __launch_bounds__(WM*WN*64) void gemm_mfma(
    const unsigned short* __restrict__ A,
    const unsigned short* __restrict__ W,
    const float* __restrict__ bias,
    float* __restrict__ Cf,
    unsigned short* __restrict__ Cb,
    int M, int N, int K){
  int tid = threadIdx.x;
  int l = tid & 63, w = tid >> 6;
  int w_n = w % WN, w_m = w / WN;
  int lr = l & 15, lk = l >> 4;
  int nb = blockIdx.x * (WN*FN*16) + w_n*(FN*16);
  int mb = blockIdx.y * (WM*FM*16) + w_m*(FM*16);
  const unsigned short* ap[FN];
  const unsigned short* bp[FM];
  #pragma unroll
  for(int i=0;i<FN;i++) ap[i] = W + (size_t)(nb + i*16 + lr)*K + lk*8;
  #pragma unroll
  for(int i=0;i<FM;i++) bp[i] = A + (size_t)(mb + i*16 + lr)*K + lk*8;
  f32x4 acc[FN][FM] = {};
  for(int k0=0;k0<K;k0+=32){
    short8 av[FN], bv[FM];
    #pragma unroll
    for(int i=0;i<FN;i++) av[i] = *(const short8*)(ap[i]);
    #pragma unroll
    for(int i=0;i<FM;i++) bv[i] = *(const short8*)(bp[i]);
    #pragma unroll
    for(int i=0;i<FN;i++)
      #pragma unroll
      for(int j=0;j<FM;j++)
        acc[i][j] = __builtin_amdgcn_mfma_f32_16x16x32_bf16(av[i], bv[j], acc[i][j], 0,0,0);
    #pragma unroll
    for(int i=0;i<FN;i++) ap[i] += 32;
    #pragma unroll
    for(int i=0;i<FM;i++) bp[i] += 32;
  }
  #pragma unroll
  for(int i=0;i<FN;i++){
    #pragma unroll
    for(int j=0;j<FM;j++){
      int m = mb + j*16 + lr;
      #pragma unroll
      for(int r=0;r<4;r++){
        int n = nb + i*16 + 4*lk + r;
        float v = acc[i][j][r];
        if(EPI==1) v = sp_f(v + bias[n]);
        if(WF) Cf[(size_t)m*N + n] = v;
        if(WB) Cb[(size_t)m*N + n] = f2bf(v);
      }
    }
  }
}

// ---------------- causal depthwise conv1d (k=4) + bias + SiLU (xz bf16) -> u_bf -----
__global__ __launch_bounds__(256) void conv1d_silu_kernel(const unsigned short* __restrict__ xz,
                                                          const float* __restrict__ cw,
                                                          const float* __restrict__ cb,
                                                          unsigned short* __restrict__ ub){
  int g = blockIdx.x*256 + threadIdx.x;   // b*2^21 + l*512 + d
  int d = g & 511;
  int l = (g>>9) & 4095;
  int b = g >> 21;
  const unsigned short* up = xz + (size_t)b*LSEQ*1024 + d;
  float accv = cb[d];
  #pragma unroll
  for(int k=0;k<4;k++){
    int ls = l-3+k;
    float vv = (ls>=0) ? bf2f(up[(size_t)ls*1024]) : 0.f;
    accv += vv * cw[d*4+k];
  }
  ub[(size_t)g] = f2bf(silu_f(accv));
}

// ================= chunked selective scan (dt,u bf16; xdbl fp32 [B|C] 32/row) =======
__global__ __launch_bounds__(256) void scan_pass1(const unsigned short* __restrict__ dt,
                                                  const unsigned short* __restrict__ u,
                                                  const float* __restrict__ xdbl,
                                                  const float* __restrict__ A_log,
                                                  float* __restrict__ Ap,
                                                  float* __restrict__ Ep){
  int G = blockIdx.x*256 + threadIdx.x;
  int s  = G & 15;
  int dl = (G>>4)&3;
  int c  = (G>>6)&63;
  int dh = (G>>12)&127;
  int b  = G>>19;
  int d  = dh*4 + dl;
  float a = -__expf(A_log[d*16+s]);
  const unsigned short* dtp = dt + (size_t)b*LSEQ*512 + d;
  const unsigned short* up  = u  + (size_t)b*LSEQ*512 + d;
  const float* xb  = xdbl + (size_t)b*LSEQ*32;
  int t0 = c*CHL;
  float aprod = 1.f, h = 0.f;
  for(int tt=0;tt<CHL;tt++){
    int t = t0+tt;
    float dtv = bf2f(dtp[(size_t)t*512]);
    float uv  = bf2f(up[(size_t)t*512]);
    float bv  = xb[t*32 + s];
    float dA  = __expf(dtv*a);
    h = dA*h + dtv*bv*uv;
    aprod *= dA;
  }
  int idx = b*8192 + d*16 + s;       // 0..16383
  Ap[(size_t)c*16384 + idx] = aprod;
  Ep[(size_t)c*16384 + idx] = h;
}

__global__ __launch_bounds__(256) void scan_pass2(const float* __restrict__ Ap,
                                                  float* __restrict__ Ep){
  int idx = blockIdx.x*256 + threadIdx.x;   // 0..16383
  float h = 0.f;
  for(int c=0;c<NCH;c++){
    float a = Ap[(size_t)c*16384 + idx];
    float e = Ep[(size_t)c*16384 + idx];
    Ep[(size_t)c*16384 + idx] = h;
    h = a*h + e;
  }
}

__global__ __launch_bounds__(256) void scan_pass3(const unsigned short* __restrict__ dt,
                                                  const unsigned short* __restrict__ u,
                                                  const unsigned short* __restrict__ xz,
                                                  const float* __restrict__ xdbl,
                                                  const float* __restrict__ A_log,
                                                  const float* __restrict__ Ep,
                                                  const float* __restrict__ Dsk,
                                                  unsigned short* __restrict__ yb){
  int G = blockIdx.x*256 + threadIdx.x;
  int s  = G & 15;
  int dl = (G>>4)&3;
  int c  = (G>>6)&63;
  int dh = (G>>12)&127;
  int b  = G>>19;
  int d  = dh*4 + dl;
  float a = -__expf(A_log[d*16+s]);
  const unsigned short* dtp = dt + (size_t)b*LSEQ*512 + d;
  const unsigned short* up  = u  + (size_t)b*LSEQ*512 + d;
  const float* xb  = xdbl + (size_t)b*LSEQ*32;
  unsigned short* yp = yb + (size_t)b*LSEQ*512 + d;
  int idx = b*8192 + d*16 + s;
  float h = Ep[(size_t)c*16384 + idx];
  float dskv = Dsk[d];
  int t0 = c*CHL;
  for(int tt=0;tt<CHL;tt++){
    int t = t0+tt;
    float dtv = bf2f(dtp[(size_t)t*512]);
    float uv  = bf2f(up[(size_t)t*512]);
    float bv  = xb[t*32 + s];
    float cv  = xb[t*32 + 16 + s];
    float dA  = __expf(dtv*a);
    h = dA*h + dtv*bv*uv;
    float pp = h*cv;
    pp += __shfl_xor(pp,1);
    pp += __shfl_xor(pp,2);
    pp += __shfl_xor(pp,4);
    pp += __shfl_xor(pp,8);
    if(s==0){
      float z = bf2f(xz[(size_t)(b*LSEQ + t)*1024 + 512 + d]);
      yp[(size_t)t*512] = f2bf((pp + uv*dskv) * silu_f(z));
    }
  }
}

// ================= conv3d via bf16 MFMA implicit GEMM ===============================
// single-writer padded fill: every byte of xt written exactly once per call.
__global__ __launch_bounds__(256) void xt_fill(const float* __restrict__ x,
                                               unsigned short* __restrict__ xt){
  int bid = blockIdx.x;
  int b = bid / 324; int r = bid - b*324;
  int zz = r / 18, yy = r - zz*18;
  bool inner = (zz>=1 && zz<=16 && yy>=1 && yy<=16);
  unsigned short* xd = xt + (size_t)((b*18 + zz)*18 + yy)*18*256;
  const float* xs = x + (size_t)b*256*4096 + (zz-1)*256 + (yy-1)*16;
  int t = threadIdx.x;
  for(int u = t; u < 576; u += 256){
    int xpos = u >> 5;           // 0..17
    int ci0 = (u & 31) * 8;
    uint4 val = make_uint4(0,0,0,0);
    if(inner && xpos>=1 && xpos<=16){
      int xi = xpos-1;
      unsigned pk[4];
      #pragma unroll
      for(int j=0;j<4;j++){
        unsigned short lo = f2bf(xs[(size_t)(ci0+2*j  )*4096 + xi]);
        unsigned short hi = f2bf(xs[(size_t)(ci0+2*j+1)*4096 + xi]);
        pk[j] = (unsigned)lo | ((unsigned)hi << 16);
      }
      val = make_uint4(pk[0],pk[1],pk[2],pk[3]);
    }
    *(uint4*)(xd + (size_t)u*8) = val;
  }
}

__global__ __launch_bounds__(256) void wt_conv(const float* __restrict__ w3,
                                               unsigned short* __restrict__ wt){
  int idx = blockIdx.x*256 + threadIdx.x;   // 0..1,769,471
  int ci = idx & 255; int r = idx >> 8;     // 0..6911
  int tap = r % 27, co = r / 27;
  wt[idx] = f2bf(w3[(size_t)co*6912 + ci*27 + tap]);
}

// 256 blocks x 512 threads. XCD partition: xcd=bid&7 -> (co-64-group cg, m-half mh);
// per-XCD L2 working set = wt slice 884 KB + xt half 1.7 MB < 4 MB (resident).
// 8 waves = 2(co-32) x 4(m-32); wave tile 32co x 32m. Per tap: batch-load 32 frags
// into registers (32 loads in flight), then 32 MFMAs. Fused prelu+skip epilogue.
__global__ __launch_bounds__(512) void conv3d_mfma(const unsigned short* __restrict__ xt,
                                                   const unsigned short* __restrict__ wt,
                                                   const unsigned short* __restrict__ hb,
                                                   const float* __restrict__ prelu_a,
                                                   const float* __restrict__ scale,
                                                   float* __restrict__ out){
  int bid = blockIdx.x;
  int xcd = bid & 7, j = bid >> 3;          // j: 0..31
  int cg = xcd >> 1, mh = xcd & 1;
  int tid = threadIdx.x;
  int l = tid & 63, w = tid >> 6;           // 8 waves
  int wcg = w & 1, mg = w >> 1;             // co-32 group, m-32 group
  int lr = l & 15, lk = l >> 4;

  int cobase = cg*64 + wcg*32;
  int m0 = mh*4096 + j*128 + mg*32 + lr;    // lane's m (fm=0)
  int b = m0 >> 12, sp0 = m0 & 4095;
  int z = sp0 >> 8, y = (sp0 >> 4) & 15, x = sp0 & 15;
  const unsigned short* bbase = xt + (size_t)(((b*18 + z+1)*18 + (y+1))*18 + (x+1))*256 + lk*8;
  const unsigned short* abase = wt + (size_t)(cobase + lr)*6912 + lk*8;

  f32x4 acc[2][2] = {};
  for(int tap=0; tap<27; ++tap){
    int dz = tap/9 - 1; int rem = tap - (tap/9)*9;
    int dy = rem/3 - 1, dx = rem - (rem/3)*3 - 1;
    const unsigned short* ap = abase + tap*256;
    const unsigned short* bp = bbase + (dz*324 + dy*18 + dx)*256;
    short8 Af[2][8], Bf[2][8];
    #pragma unroll
    for(int c8=0;c8<8;c8++){
      Af[0][c8] = *(const short8*)(ap + c8*32);
      Af[1][c8] = *(const short8*)(ap + 16*6912 + c8*32);
      Bf[0][c8] = *(const short8*)(bp + c8*32);
      Bf[1][c8] = *(const short8*)(bp + 4608 + c8*32);   // +16 m = +1 y-row
    }
    #pragma unroll
    for(int c8=0;c8<8;c8++){
      acc[0][0] = __builtin_amdgcn_mfma_f32_16x16x32_bf16(Af[0][c8], Bf[0][c8], acc[0][0], 0,0,0);
      acc[0][1] = __builtin_amdgcn_mfma_f32_16x16x32_bf16(Af[0][c8], Bf[1][c8], acc[0][1], 0,0,0);
      acc[1][0] = __builtin_amdgcn_mfma_f32_16x16x32_bf16(Af[1][c8], Bf[0][c8], acc[1][0], 0,0,0);
      acc[1][1] = __builtin_amdgcn_mfma_f32_16x16x32_bf16(Af[1][c8], Bf[1][c8], acc[1][1], 0,0,0);
    }
  }
  float spv = sp_f(scale[0]);
  float pa = prelu_a[0];
  #pragma unroll
  for(int fc=0; fc<2; ++fc){
    #pragma unroll
    for(int fm=0; fm<2; ++fm){
      int m = mh*4096 + j*128 + mg*32 + fm*16 + lr;
      int bb = m >> 12, sp = m & 4095;
      #pragma unroll
      for(int r=0; r<4; ++r){
        int co = cobase + fc*16 + 4*lk + r;
        float cval = acc[fc][fm][r];
        float pr = cval > 0.f ? cval : pa*cval;
        out[((size_t)(bb*256 + co))*4096 + sp] = bf2f(hb[(size_t)m*256 + co]) + spv*pr;
      }
    }
  }
}

extern "C" void kernel_launch(void* const* d_in, const int* in_sizes, int n_in,
                              void* d_out, int out_size, void* d_ws, size_t ws_size,
                              hipStream_t stream) {
  const float* x         = (const float*)d_in[0];
  const float* ln_w      = (const float*)d_in[1];
  const float* ln_b      = (const float*)d_in[2];
  const float* in_proj_w = (const float*)d_in[3];
  const float* conv_w    = (const float*)d_in[4];
  const float* conv_b    = (const float*)d_in[5];
  const float* x_proj_w  = (const float*)d_in[6];
  const float* dt_proj_w = (const float*)d_in[7];
  const float* dt_proj_b = (const float*)d_in[8];
  const float* A_log     = (const float*)d_in[9];
  const float* D_skip    = (const float*)d_in[10];
  const float* out_proj_w= (const float*)d_in[11];
  const float* conv3d_w  = (const float*)d_in[12];
  const float* prelu_a   = (const float*)d_in[13];
  const float* scale     = (const float*)d_in[14];
  float* out = (float*)d_out;

  // workspace layout (float offsets) — NO aliasing; one producer per phase.
  float* ws   = (float*)d_ws;
  float* Ap   = ws;                               // 1,048,576 fl
  float* Ep   = Ap + 1048576;                     // 1,048,576 fl
  unsigned short* xz_bf = (unsigned short*)(Ep + 1048576);     // 8,388,608 bf16
  unsigned short* u_bf  = xz_bf + 8388608;        // 4,194,304 bf16
  float* xdbl = (float*)(u_bf + 4194304);         // 262,144 fl
  unsigned short* dt_bf = (unsigned short*)(xdbl + 262144);    // 4,194,304 bf16
  unsigned short* h_bf  = dt_bf + 4194304;        // 2,097,152 bf16
  unsigned short* y_bf  = h_bf + 2097152;         // 4,194,304 bf16
  unsigned short* inw_bf   = y_bf + 4194304;      // 524,288 bf16
  unsigned short* ow_bf    = inw_bf + 524288;     // 262,144 bf16
  unsigned short* xpwbc_bf = ow_bf + 262144;      // 32,768 bf16
  unsigned short* wdt_bf   = xpwbc_bf + 32768;    // 524,288 bf16
  const size_t base_floats = 14565376;            // 58,261,504 bytes
  // xt/wt at dedicated tail (ws >= 77,070,336 B established by rounds 1-4 layouts)
  unsigned short* xt = (unsigned short*)(ws + base_floats);
  unsigned short* wt = xt + 2985984;

  // ---- weight prep (bf16) ----
  cvt_bf<<<2048, 256, 0, stream>>>(in_proj_w, inw_bf, 524288);
  cvt_bf<<<1024, 256, 0, stream>>>(out_proj_w, ow_bf, 262144);
  cvt_bf<<<64, 256, 0, stream>>>(x_proj_w + 16*512, xpwbc_bf, 16384);
  cvt_bf<<<64, 256, 0, stream>>>(x_proj_w + 48*512 + 16*512, xpwbc_bf + 16384, 16384);
  wdt_kernel<<<2048, 256, 0, stream>>>(dt_proj_w, x_proj_w, wdt_bf);

  ln_kernel<<<LSEQ*2, 64, 0, stream>>>(x, ln_w, ln_b, h_bf);

  for(int dep=0; dep<2; dep++){
    const unsigned short* inw = inw_bf   + (size_t)dep*262144;
    const unsigned short* oww = ow_bf    + (size_t)dep*131072;
    const unsigned short* xpw = xpwbc_bf + (size_t)dep*16384;
    const unsigned short* wdt = wdt_bf   + (size_t)dep*262144;
    const float* cw   = conv_w    + (size_t)dep*512*4;
    const float* cb   = conv_b    + (size_t)dep*512;
    const float* dtb  = dt_proj_b + (size_t)dep*512;
    const float* Alg  = A_log     + (size_t)dep*512*16;
    const float* Dsk  = D_skip    + (size_t)dep*512;

    // in_proj: xz_bf[8192,1024] = h_bf @ inw^T   (512 blocks)
    gemm_mfma<4,4,2,2,0,0,1><<<dim3(8,64), 256, 0, stream>>>(
        h_bf, inw, nullptr, nullptr, xz_bf, 8192, 1024, 256);
    conv1d_silu_kernel<<<16384, 256, 0, stream>>>(xz_bf, cw, cb, u_bf);
    // x_proj B,C: xdbl[8192,32] = u_bf @ xpw_bc^T  (256 blocks)
    gemm_mfma<1,1,2,2,0,1,0><<<dim3(1,256), 256, 0, stream>>>(
        u_bf, xpw, nullptr, xdbl, nullptr, 8192, 32, 512);
    // dt (folded): dt_bf[8192,512] = softplus(u_bf @ wdt^T + dtb)  (512 blocks)
    gemm_mfma<2,4,2,2,1,0,1><<<dim3(4,128), 256, 0, stream>>>(
        u_bf, wdt, dtb, nullptr, dt_bf, 8192, 512, 512);

    scan_pass1<<<4096, 256, 0, stream>>>(dt_bf, u_bf, xdbl, Alg, Ap, Ep);
    scan_pass2<<<64, 256, 0, stream>>>(Ap, Ep);
    scan_pass3<<<4096, 256, 0, stream>>>(dt_bf, u_bf, xz_bf, xdbl, Alg, Ep, Dsk, y_bf);

    // out_proj: h_bf[8192,256] = y_bf @ ow^T  (512 blocks)
    gemm_mfma<1,4,2,2,0,0,1><<<dim3(2,256), 256, 0, stream>>>(
        y_bf, oww, nullptr, nullptr, h_bf, 8192, 256, 512);
  }

  // conv3d: prep + register-batched MFMA conv with fused epilogue
  xt_fill<<<648, 256, 0, stream>>>(x, xt);
  wt_conv<<<6912, 256, 0, stream>>>(conv3d_w, wt);
  conv3d_mfma<<<256, 512, 0, stream>>>(xt, wt, h_bf, prelu_a, scale, out);
}

// Round 12
// 684.352 us; speedup vs baseline: 1.0381x; 1.0381x over previous
//
#include <hip/hip_runtime.h>
#include <math.h>

#define LSEQ 4096
#define DIMC 256
#define DI   512
#define NCH  64     // chunks over L
#define CHL  64     // chunk length

typedef short short8 __attribute__((ext_vector_type(8)));
typedef float f32x4 __attribute__((ext_vector_type(4)));

__device__ __forceinline__ float sp_f(float v){ return fmaxf(v,0.f) + log1pf(__expf(-fabsf(v))); }
__device__ __forceinline__ float silu_f(float v){ return v/(1.f+__expf(-v)); }
__device__ __forceinline__ unsigned short f2bf(float f){
  unsigned u = __builtin_bit_cast(unsigned, f);
  unsigned r = (u + 0x7FFFu + ((u>>16)&1u)) >> 16;
  return (unsigned short)r;
}
__device__ __forceinline__ float bf2f(unsigned short us){
  unsigned u = ((unsigned)us)<<16;
  return __builtin_bit_cast(float, u);
}

// ---------------- LayerNorm: x (B,C,L) -> h_bf (B*L, C) bf16 -------------------------
__global__ __launch_bounds__(64) void ln_kernel(const float* __restrict__ x,
                                                const float* __restrict__ w,
                                                const float* __restrict__ bias,
                                                unsigned short* __restrict__ hb){
  int row = blockIdx.x;            // b*L + l
  int b = row >> 12, l = row & 4095;
  int i = threadIdx.x;             // 0..63
  const float* xb = x + (size_t)b*DIMC*LSEQ + l;
  float v[4]; float s=0.f, sq=0.f;
  #pragma unroll
  for(int j=0;j<4;j++){ float t = xb[(size_t)(j*64+i)*LSEQ]; v[j]=t; s+=t; sq+=t*t; }
  #pragma unroll
  for(int o=1;o<64;o<<=1){ s += __shfl_xor(s,o); sq += __shfl_xor(sq,o); }
  float mu = s*(1.f/256.f);
  float var = sq*(1.f/256.f) - mu*mu;
  float rs = rsqrtf(var + 1e-5f);
  unsigned short* hr = hb + (size_t)row*DIMC;
  #pragma unroll
  for(int j=0;j<4;j++){ int c=j*64+i; hr[c] = f2bf((v[j]-mu)*rs*w[c] + bias[c]); }
}

// ---------------- generic bf16 copy of weights ---------------------------------------
__global__ __launch_bounds__(256) void cvt_bf(const float* __restrict__ src,
                                              unsigned short* __restrict__ dst, int n){
  int i = blockIdx.x*256 + threadIdx.x;
  if(i < n) dst[i] = f2bf(src[i]);
}

// ---------------- W_dt[dep][n][k] = sum_j dtw[dep][n][j] * xpw[dep][j][k] ------------
__global__ __launch_bounds__(256) void wdt_kernel(const float* __restrict__ dtw,
                                                  const float* __restrict__ xpw,
                                                  unsigned short* __restrict__ wdt){
  int idx = blockIdx.x*256 + threadIdx.x;   // 0..524287
  int dep = idx >> 18;
  int r = idx & 262143;
  int n = r >> 9, k = r & 511;
  const float* dw = dtw + (size_t)dep*512*16 + n*16;
  const float* xp = xpw + (size_t)dep*48*512 + k;
  float acc = 0.f;
  #pragma unroll
  for(int j=0;j<16;j++) acc += dw[j] * xp[(size_t)j*512];
  wdt[idx] = f2bf(acc);
}

// ---------------- all-global bf16 MFMA GEMM: D[n][m] = W[n,:]·A[m,:] -----------------
template<int FM,int FN,int WM,int WN,int EPI,int WF,int WB>
__global__ __launch_bounds__(WM*WN*64) void gemm_mfma(
    const unsigned short* __restrict__ A,
    const unsigned short* __restrict__ W,
    const float* __restrict__ bias,
    float* __restrict__ Cf,
    unsigned short* __restrict__ Cb,
    int M, int N, int K){
  int tid = threadIdx.x;
  int l = tid & 63, w = tid >> 6;
  int w_n = w % WN, w_m = w / WN;
  int lr = l & 15, lk = l >> 4;
  int nb = blockIdx.x * (WN*FN*16) + w_n*(FN*16);
  int mb = blockIdx.y * (WM*FM*16) + w_m*(FM*16);
  const unsigned short* ap[FN];
  const unsigned short* bp[FM];
  #pragma unroll
  for(int i=0;i<FN;i++) ap[i] = W + (size_t)(nb + i*16 + lr)*K + lk*8;
  #pragma unroll
  for(int i=0;i<FM;i++) bp[i] = A + (size_t)(mb + i*16 + lr)*K + lk*8;
  f32x4 acc[FN][FM] = {};
  for(int k0=0;k0<K;k0+=32){
    short8 av[FN], bv[FM];
    #pragma unroll
    for(int i=0;i<FN;i++) av[i] = *(const short8*)(ap[i]);
    #pragma unroll
    for(int i=0;i<FM;i++) bv[i] = *(const short8*)(bp[i]);
    #pragma unroll
    for(int i=0;i<FN;i++)
      #pragma unroll
      for(int j=0;j<FM;j++)
        acc[i][j] = __builtin_amdgcn_mfma_f32_16x16x32_bf16(av[i], bv[j], acc[i][j], 0,0,0);
    #pragma unroll
    for(int i=0;i<FN;i++) ap[i] += 32;
    #pragma unroll
    for(int i=0;i<FM;i++) bp[i] += 32;
  }
  #pragma unroll
  for(int i=0;i<FN;i++){
    #pragma unroll
    for(int j=0;j<FM;j++){
      int m = mb + j*16 + lr;
      #pragma unroll
      for(int r=0;r<4;r++){
        int n = nb + i*16 + 4*lk + r;
        float v = acc[i][j][r];
        if(EPI==1) v = sp_f(v + bias[n]);
        if(WF) Cf[(size_t)m*N + n] = v;
        if(WB) Cb[(size_t)m*N + n] = f2bf(v);
      }
    }
  }
}

// ---------------- causal depthwise conv1d (k=4) + bias + SiLU (xz bf16) -> u_bf -----
__global__ __launch_bounds__(256) void conv1d_silu_kernel(const unsigned short* __restrict__ xz,
                                                          const float* __restrict__ cw,
                                                          const float* __restrict__ cb,
                                                          unsigned short* __restrict__ ub){
  int g = blockIdx.x*256 + threadIdx.x;   // b*2^21 + l*512 + d
  int d = g & 511;
  int l = (g>>9) & 4095;
  int b = g >> 21;
  const unsigned short* up = xz + (size_t)b*LSEQ*1024 + d;
  float accv = cb[d];
  #pragma unroll
  for(int k=0;k<4;k++){
    int ls = l-3+k;
    float vv = (ls>=0) ? bf2f(up[(size_t)ls*1024]) : 0.f;
    accv += vv * cw[d*4+k];
  }
  ub[(size_t)g] = f2bf(silu_f(accv));
}

// ================= chunked selective scan (dt,u bf16; xdbl fp32 [B|C] 32/row) =======
__global__ __launch_bounds__(256) void scan_pass1(const unsigned short* __restrict__ dt,
                                                  const unsigned short* __restrict__ u,
                                                  const float* __restrict__ xdbl,
                                                  const float* __restrict__ A_log,
                                                  float* __restrict__ Ap,
                                                  float* __restrict__ Ep){
  int G = blockIdx.x*256 + threadIdx.x;
  int s  = G & 15;
  int dl = (G>>4)&3;
  int c  = (G>>6)&63;
  int dh = (G>>12)&127;
  int b  = G>>19;
  int d  = dh*4 + dl;
  float a = -__expf(A_log[d*16+s]);
  const unsigned short* dtp = dt + (size_t)b*LSEQ*512 + d;
  const unsigned short* up  = u  + (size_t)b*LSEQ*512 + d;
  const float* xb  = xdbl + (size_t)b*LSEQ*32;
  int t0 = c*CHL;
  float aprod = 1.f, h = 0.f;
  for(int tt=0;tt<CHL;tt++){
    int t = t0+tt;
    float dtv = bf2f(dtp[(size_t)t*512]);
    float uv  = bf2f(up[(size_t)t*512]);
    float bv  = xb[t*32 + s];
    float dA  = __expf(dtv*a);
    h = dA*h + dtv*bv*uv;
    aprod *= dA;
  }
  int idx = b*8192 + d*16 + s;       // 0..16383
  Ap[(size_t)c*16384 + idx] = aprod;
  Ep[(size_t)c*16384 + idx] = h;
}

__global__ __launch_bounds__(256) void scan_pass2(const float* __restrict__ Ap,
                                                  float* __restrict__ Ep){
  int idx = blockIdx.x*256 + threadIdx.x;   // 0..16383
  float h = 0.f;
  for(int c=0;c<NCH;c++){
    float a = Ap[(size_t)c*16384 + idx];
    float e = Ep[(size_t)c*16384 + idx];
    Ep[(size_t)c*16384 + idx] = h;
    h = a*h + e;
  }
}

__global__ __launch_bounds__(256) void scan_pass3(const unsigned short* __restrict__ dt,
                                                  const unsigned short* __restrict__ u,
                                                  const unsigned short* __restrict__ xz,
                                                  const float* __restrict__ xdbl,
                                                  const float* __restrict__ A_log,
                                                  const float* __restrict__ Ep,
                                                  const float* __restrict__ Dsk,
                                                  unsigned short* __restrict__ yb){
  int G = blockIdx.x*256 + threadIdx.x;
  int s  = G & 15;
  int dl = (G>>4)&3;
  int c  = (G>>6)&63;
  int dh = (G>>12)&127;
  int b  = G>>19;
  int d  = dh*4 + dl;
  float a = -__expf(A_log[d*16+s]);
  const unsigned short* dtp = dt + (size_t)b*LSEQ*512 + d;
  const unsigned short* up  = u  + (size_t)b*LSEQ*512 + d;
  const float* xb  = xdbl + (size_t)b*LSEQ*32;
  unsigned short* yp = yb + (size_t)b*LSEQ*512 + d;
  int idx = b*8192 + d*16 + s;
  float h = Ep[(size_t)c*16384 + idx];
  float dskv = Dsk[d];
  int t0 = c*CHL;
  for(int tt=0;tt<CHL;tt++){
    int t = t0+tt;
    float dtv = bf2f(dtp[(size_t)t*512]);
    float uv  = bf2f(up[(size_t)t*512]);
    float bv  = xb[t*32 + s];
    float cv  = xb[t*32 + 16 + s];
    float dA  = __expf(dtv*a);
    h = dA*h + dtv*bv*uv;
    float pp = h*cv;
    pp += __shfl_xor(pp,1);
    pp += __shfl_xor(pp,2);
    pp += __shfl_xor(pp,4);
    pp += __shfl_xor(pp,8);
    if(s==0){
      float z = bf2f(xz[(size_t)(b*LSEQ + t)*1024 + 512 + d]);
      yp[(size_t)t*512] = f2bf((pp + uv*dskv) * silu_f(z));
    }
  }
}

// ================= conv3d via bf16 MFMA implicit GEMM (9-way tap split) =============
// single-writer padded fill: every byte of xt written exactly once per call.
__global__ __launch_bounds__(256) void xt_fill(const float* __restrict__ x,
                                               unsigned short* __restrict__ xt){
  int bid = blockIdx.x;
  int b = bid / 324; int r = bid - b*324;
  int zz = r / 18, yy = r - zz*18;
  bool inner = (zz>=1 && zz<=16 && yy>=1 && yy<=16);
  unsigned short* xd = xt + (size_t)((b*18 + zz)*18 + yy)*18*256;
  const float* xs = x + (size_t)b*256*4096 + (zz-1)*256 + (yy-1)*16;
  int t = threadIdx.x;
  for(int u = t; u < 576; u += 256){
    int xpos = u >> 5;           // 0..17
    int ci0 = (u & 31) * 8;
    uint4 val = make_uint4(0,0,0,0);
    if(inner && xpos>=1 && xpos<=16){
      int xi = xpos-1;
      unsigned pk[4];
      #pragma unroll
      for(int j=0;j<4;j++){
        unsigned short lo = f2bf(xs[(size_t)(ci0+2*j  )*4096 + xi]);
        unsigned short hi = f2bf(xs[(size_t)(ci0+2*j+1)*4096 + xi]);
        pk[j] = (unsigned)lo | ((unsigned)hi << 16);
      }
      val = make_uint4(pk[0],pk[1],pk[2],pk[3]);
    }
    *(uint4*)(xd + (size_t)u*8) = val;
  }
}

__global__ __launch_bounds__(256) void wt_conv(const float* __restrict__ w3,
                                               unsigned short* __restrict__ wt){
  int idx = blockIdx.x*256 + threadIdx.x;   // 0..1,769,471
  int ci = idx & 255; int r = idx >> 8;     // 0..6911
  int tap = r % 27, co = r / 27;
  wt[idx] = f2bf(w3[(size_t)co*6912 + ci*27 + tap]);
}

// 2304 blocks = 9 tap-groups (dz,dy) x 256 m-tiles (32m x 256co); 3 taps (dx) each.
// R10's proven block shape (4 waves = co quadrants, B loads L1-shared, 6:8 load:MFMA)
// at 36 waves/CU requested -> ~8 waves/SIMD for latency hiding. bf16 partials,
// single writer per element: g<8 -> p07 plane g, g==8 -> p8.
__global__ __launch_bounds__(256) void conv3d_part(const unsigned short* __restrict__ xt,
                                                   const unsigned short* __restrict__ wt,
                                                   unsigned short* __restrict__ p07,
                                                   unsigned short* __restrict__ p8){
  int bid = blockIdx.x;
  int g = bid >> 8;             // 0..8 = (dz+1)*3 + (dy+1)
  int mtile = bid & 255;        // 0..255 (32 m each)
  int gz = g/3, gy = g - gz*3;  // gz=dz+1, gy=dy+1
  int tid = threadIdx.x;
  int l  = tid & 63;
  int w  = tid >> 6;            // co quadrant (64 co)
  int lr = l & 15;
  int lk = l >> 4;

  const unsigned short* abase = wt + (size_t)(w*64 + lr)*6912 + (g*3)*256 + lk*8;
  int m0 = mtile*32 + lr;
  int b = m0 >> 12, sp0 = m0 & 4095;
  int z = sp0 >> 8, y = (sp0 >> 4) & 15, x = sp0 & 15;
  // padded coords: zz = z+1+dz = z+gz, yy = y+1+dy = y+gy, xx = x+1+dx
  const unsigned short* bbase = xt
      + (size_t)(((b*18 + z + gz)*18 + (y + gy))*18 + (x+1))*256 + lk*8;

  f32x4 acc[4][2] = {};
  for(int t=0; t<3; ++t){       // dx = t-1
    const unsigned short* ap = abase + t*256;
    const unsigned short* bp = bbase + (t-1)*256;
    #pragma unroll
    for(int c8=0; c8<8; ++c8){
      short8 b0 = *(const short8*)(bp);
      short8 b1 = *(const short8*)(bp + 4608);     // +16 m = +1 y-row (even-y tiles)
      short8 a0 = *(const short8*)(ap);
      short8 a1 = *(const short8*)(ap + 16*6912);
      short8 a2 = *(const short8*)(ap + 32*6912);
      short8 a3 = *(const short8*)(ap + 48*6912);
      acc[0][0] = __builtin_amdgcn_mfma_f32_16x16x32_bf16(a0, b0, acc[0][0], 0,0,0);
      acc[0][1] = __builtin_amdgcn_mfma_f32_16x16x32_bf16(a0, b1, acc[0][1], 0,0,0);
      acc[1][0] = __builtin_amdgcn_mfma_f32_16x16x32_bf16(a1, b0, acc[1][0], 0,0,0);
      acc[1][1] = __builtin_amdgcn_mfma_f32_16x16x32_bf16(a1, b1, acc[1][1], 0,0,0);
      acc[2][0] = __builtin_amdgcn_mfma_f32_16x16x32_bf16(a2, b0, acc[2][0], 0,0,0);
      acc[2][1] = __builtin_amdgcn_mfma_f32_16x16x32_bf16(a2, b1, acc[2][1], 0,0,0);
      acc[3][0] = __builtin_amdgcn_mfma_f32_16x16x32_bf16(a3, b0, acc[3][0], 0,0,0);
      acc[3][1] = __builtin_amdgcn_mfma_f32_16x16x32_bf16(a3, b1, acc[3][1], 0,0,0);
      ap += 32; bp += 32;
    }
  }
  unsigned short* pg = (g < 8) ? (p07 + (size_t)g*2097152) : p8;
  #pragma unroll
  for(int fc=0; fc<4; ++fc){
    #pragma unroll
    for(int fm=0; fm<2; ++fm){
      int m = mtile*32 + fm*16 + lr;
      int bb = m >> 12, sp = m & 4095;
      #pragma unroll
      for(int r=0; r<4; ++r){
        int co = w*64 + fc*16 + 4*lk + r;
        pg[((size_t)(bb*256 + co))*4096 + sp] = f2bf(acc[fc][fm][r]);
      }
    }
  }
}

// combine: out = hb + softplus(scale)*prelu(sum of 9 bf16 partials); 512 blocks=(b,co)
__global__ __launch_bounds__(256) void conv3d_combine(const unsigned short* __restrict__ p07,
                                                      const unsigned short* __restrict__ p8,
                                                      const unsigned short* __restrict__ hb,
                                                      const float* __restrict__ prelu_a,
                                                      const float* __restrict__ scale,
                                                      float* __restrict__ out){
  int bc = blockIdx.x;          // b*256 + co
  int b = bc >> 8, co = bc & 255;
  float spv = sp_f(scale[0]);
  float pa = prelu_a[0];
  #pragma unroll 4
  for(int it=0; it<16; ++it){
    int sp = it*256 + threadIdx.x;
    size_t o = (size_t)bc*4096 + sp;
    float v = bf2f(p8[o]);
    #pragma unroll
    for(int g=0; g<8; ++g) v += bf2f(p07[(size_t)g*2097152 + o]);
    float pr = v > 0.f ? v : pa*v;
    int m = b*4096 + sp;
    out[o] = bf2f(hb[(size_t)m*256 + co]) + spv*pr;
  }
}

extern "C" void kernel_launch(void* const* d_in, const int* in_sizes, int n_in,
                              void* d_out, int out_size, void* d_ws, size_t ws_size,
                              hipStream_t stream) {
  const float* x         = (const float*)d_in[0];
  const float* ln_w      = (const float*)d_in[1];
  const float* ln_b      = (const float*)d_in[2];
  const float* in_proj_w = (const float*)d_in[3];
  const float* conv_w    = (const float*)d_in[4];
  const float* conv_b    = (const float*)d_in[5];
  const float* x_proj_w  = (const float*)d_in[6];
  const float* dt_proj_w = (const float*)d_in[7];
  const float* dt_proj_b = (const float*)d_in[8];
  const float* A_log     = (const float*)d_in[9];
  const float* D_skip    = (const float*)d_in[10];
  const float* out_proj_w= (const float*)d_in[11];
  const float* conv3d_w  = (const float*)d_in[12];
  const float* prelu_a   = (const float*)d_in[13];
  const float* scale     = (const float*)d_in[14];
  float* out = (float*)d_out;

  // workspace layout (float offsets). conv3d partials alias the mamba region that is
  // dead at conv time and fully rewritten (before any read) next call.
  float* ws   = (float*)d_ws;
  float* Ap   = ws;                               // 1,048,576 fl
  float* Ep   = Ap + 1048576;                     // 1,048,576 fl
  unsigned short* xz_bf = (unsigned short*)(Ep + 1048576);     // 8,388,608 bf16
  unsigned short* u_bf  = xz_bf + 8388608;        // 4,194,304 bf16
  float* xdbl = (float*)(u_bf + 4194304);         // 262,144 fl
  unsigned short* dt_bf = (unsigned short*)(xdbl + 262144);    // 4,194,304 bf16
  unsigned short* h_bf  = dt_bf + 4194304;        // 2,097,152 bf16 (LIVE at conv time)
  unsigned short* y_bf  = h_bf + 2097152;         // 4,194,304 bf16 (dead after out_proj)
  unsigned short* inw_bf   = y_bf + 4194304;      // 524,288 bf16
  unsigned short* ow_bf    = inw_bf + 524288;     // 262,144 bf16
  unsigned short* xpwbc_bf = ow_bf + 262144;      // 32,768 bf16
  unsigned short* wdt_bf   = xpwbc_bf + 32768;    // 524,288 bf16
  const size_t base_floats = 14565376;            // 58,261,504 bytes
  // partial planes 0..7: 16,777,216 shorts, fits in xz..dt region (17,301,504 shorts)
  unsigned short* p07 = xz_bf;
  unsigned short* p8  = y_bf;                     // plane 8 (2,097,152 <= 4,194,304)
  // xt/wt at dedicated tail (ws >= 77,070,336 B established by rounds 1-4 layouts)
  unsigned short* xt = (unsigned short*)(ws + base_floats);
  unsigned short* wt = xt + 2985984;

  // ---- weight prep (bf16) ----
  cvt_bf<<<2048, 256, 0, stream>>>(in_proj_w, inw_bf, 524288);
  cvt_bf<<<1024, 256, 0, stream>>>(out_proj_w, ow_bf, 262144);
  cvt_bf<<<64, 256, 0, stream>>>(x_proj_w + 16*512, xpwbc_bf, 16384);
  cvt_bf<<<64, 256, 0, stream>>>(x_proj_w + 48*512 + 16*512, xpwbc_bf + 16384, 16384);
  wdt_kernel<<<2048, 256, 0, stream>>>(dt_proj_w, x_proj_w, wdt_bf);

  ln_kernel<<<LSEQ*2, 64, 0, stream>>>(x, ln_w, ln_b, h_bf);

  for(int dep=0; dep<2; dep++){
    const unsigned short* inw = inw_bf   + (size_t)dep*262144;
    const unsigned short* oww = ow_bf    + (size_t)dep*131072;
    const unsigned short* xpw = xpwbc_bf + (size_t)dep*16384;
    const unsigned short* wdt = wdt_bf   + (size_t)dep*262144;
    const float* cw   = conv_w    + (size_t)dep*512*4;
    const float* cb   = conv_b    + (size_t)dep*512;
    const float* dtb  = dt_proj_b + (size_t)dep*512;
    const float* Alg  = A_log     + (size_t)dep*512*16;
    const float* Dsk  = D_skip    + (size_t)dep*512;

    // in_proj: xz_bf[8192,1024] = h_bf @ inw^T   (512 blocks)
    gemm_mfma<4,4,2,2,0,0,1><<<dim3(8,64), 256, 0, stream>>>(
        h_bf, inw, nullptr, nullptr, xz_bf, 8192, 1024, 256);
    conv1d_silu_kernel<<<16384, 256, 0, stream>>>(xz_bf, cw, cb, u_bf);
    // x_proj B,C: xdbl[8192,32] = u_bf @ xpw_bc^T  (256 blocks)
    gemm_mfma<1,1,2,2,0,1,0><<<dim3(1,256), 256, 0, stream>>>(
        u_bf, xpw, nullptr, xdbl, nullptr, 8192, 32, 512);
    // dt (folded): dt_bf[8192,512] = softplus(u_bf @ wdt^T + dtb)  (512 blocks)
    gemm_mfma<2,4,2,2,1,0,1><<<dim3(4,128), 256, 0, stream>>>(
        u_bf, wdt, dtb, nullptr, dt_bf, 8192, 512, 512);

    scan_pass1<<<4096, 256, 0, stream>>>(dt_bf, u_bf, xdbl, Alg, Ap, Ep);
    scan_pass2<<<64, 256, 0, stream>>>(Ap, Ep);
    scan_pass3<<<4096, 256, 0, stream>>>(dt_bf, u_bf, xz_bf, xdbl, Alg, Ep, Dsk, y_bf);

    // out_proj: h_bf[8192,256] = y_bf @ ow^T  (512 blocks)
    gemm_mfma<1,4,2,2,0,0,1><<<dim3(2,256), 256, 0, stream>>>(
        y_bf, oww, nullptr, nullptr, h_bf, 8192, 256, 512);
  }

  // conv3d: prep + 9-way tap-split partials + combine epilogue
  xt_fill<<<648, 256, 0, stream>>>(x, xt);
  wt_conv<<<6912, 256, 0, stream>>>(conv3d_w, wt);
  conv3d_part<<<2304, 256, 0, stream>>>(xt, wt, p07, p8);
  conv3d_combine<<<512, 256, 0, stream>>>(p07, p8, h_bf, prelu_a, scale, out);
}

// Round 13
// 669.294 us; speedup vs baseline: 1.0614x; 1.0225x over previous
//
#include <hip/hip_runtime.h>
#include <math.h>

#define LSEQ 4096
#define DIMC 256
#define DI   512
#define NCH  64     // chunks over L
#define CHL  64     // chunk length

typedef short short8 __attribute__((ext_vector_type(8)));
typedef float f32x4 __attribute__((ext_vector_type(4)));

__device__ __forceinline__ float sp_f(float v){ return fmaxf(v,0.f) + log1pf(__expf(-fabsf(v))); }
__device__ __forceinline__ float silu_f(float v){ return v/(1.f+__expf(-v)); }
__device__ __forceinline__ unsigned short f2bf(float f){
  unsigned u = __builtin_bit_cast(unsigned, f);
  unsigned r = (u + 0x7FFFu + ((u>>16)&1u)) >> 16;
  return (unsigned short)r;
}
__device__ __forceinline__ float bf2f(unsigned short us){
  unsigned u = ((unsigned)us)<<16;
  return __builtin_bit_cast(float, u);
}

// ---------------- LayerNorm: x (B,C,L) -> h_bf (B*L, C) bf16 -------------------------
__global__ __launch_bounds__(64) void ln_kernel(const float* __restrict__ x,
                                                const float* __restrict__ w,
                                                const float* __restrict__ bias,
                                                unsigned short* __restrict__ hb){
  int row = blockIdx.x;            // b*L + l
  int b = row >> 12, l = row & 4095;
  int i = threadIdx.x;             // 0..63
  const float* xb = x + (size_t)b*DIMC*LSEQ + l;
  float v[4]; float s=0.f, sq=0.f;
  #pragma unroll
  for(int j=0;j<4;j++){ float t = xb[(size_t)(j*64+i)*LSEQ]; v[j]=t; s+=t; sq+=t*t; }
  #pragma unroll
  for(int o=1;o<64;o<<=1){ s += __shfl_xor(s,o); sq += __shfl_xor(sq,o); }
  float mu = s*(1.f/256.f);
  float var = sq*(1.f/256.f) - mu*mu;
  float rs = rsqrtf(var + 1e-5f);
  unsigned short* hr = hb + (size_t)row*DIMC;
  #pragma unroll
  for(int j=0;j<4;j++){ int c=j*64+i; hr[c] = f2bf((v[j]-mu)*rs*w[c] + bias[c]); }
}

// ---------------- generic bf16 copy of weights ---------------------------------------
__global__ __launch_bounds__(256) void cvt_bf(const float* __restrict__ src,
                                              unsigned short* __restrict__ dst, int n){
  int i = blockIdx.x*256 + threadIdx.x;
  if(i < n) dst[i] = f2bf(src[i]);
}

// ---------------- W_dt[dep][n][k] = sum_j dtw[dep][n][j] * xpw[dep][j][k] ------------
__global__ __launch_bounds__(256) void wdt_kernel(const float* __restrict__ dtw,
                                                  const float* __restrict__ xpw,
                                                  unsigned short* __restrict__ wdt){
  int idx = blockIdx.x*256 + threadIdx.x;   // 0..524287
  int dep = idx >> 18;
  int r = idx & 262143;
  int n = r >> 9, k = r & 511;
  const float* dw = dtw + (size_t)dep*512*16 + n*16;
  const float* xp = xpw + (size_t)dep*48*512 + k;
  float acc = 0.f;
  #pragma unroll
  for(int j=0;j<16;j++) acc += dw[j] * xp[(size_t)j*512];
  wdt[idx] = f2bf(acc);
}

// ---------------- all-global bf16 MFMA GEMM: D[n][m] = W[n,:]·A[m,:] -----------------
template<int FM,int FN,int WM,int WN,int EPI,int WF,int WB>
__global__ __launch_bounds__(WM*WN*64) void gemm_mfma(
    const unsigned short* __restrict__ A,
    const unsigned short* __restrict__ W,
    const float* __restrict__ bias,
    float* __restrict__ Cf,
    unsigned short* __restrict__ Cb,
    int M, int N, int K){
  int tid = threadIdx.x;
  int l = tid & 63, w = tid >> 6;
  int w_n = w % WN, w_m = w / WN;
  int lr = l & 15, lk = l >> 4;
  int nb = blockIdx.x * (WN*FN*16) + w_n*(FN*16);
  int mb = blockIdx.y * (WM*FM*16) + w_m*(FM*16);
  const unsigned short* ap[FN];
  const unsigned short* bp[FM];
  #pragma unroll
  for(int i=0;i<FN;i++) ap[i] = W + (size_t)(nb + i*16 + lr)*K + lk*8;
  #pragma unroll
  for(int i=0;i<FM;i++) bp[i] = A + (size_t)(mb + i*16 + lr)*K + lk*8;
  f32x4 acc[FN][FM] = {};
  for(int k0=0;k0<K;k0+=32){
    short8 av[FN], bv[FM];
    #pragma unroll
    for(int i=0;i<FN;i++) av[i] = *(const short8*)(ap[i]);
    #pragma unroll
    for(int i=0;i<FM;i++) bv[i] = *(const short8*)(bp[i]);
    #pragma unroll
    for(int i=0;i<FN;i++)
      #pragma unroll
      for(int j=0;j<FM;j++)
        acc[i][j] = __builtin_amdgcn_mfma_f32_16x16x32_bf16(av[i], bv[j], acc[i][j], 0,0,0);
    #pragma unroll
    for(int i=0;i<FN;i++) ap[i] += 32;
    #pragma unroll
    for(int i=0;i<FM;i++) bp[i] += 32;
  }
  #pragma unroll
  for(int i=0;i<FN;i++){
    #pragma unroll
    for(int j=0;j<FM;j++){
      int m = mb + j*16 + lr;
      #pragma unroll
      for(int r=0;r<4;r++){
        int n = nb + i*16 + 4*lk + r;
        float v = acc[i][j][r];
        if(EPI==1) v = sp_f(v + bias[n]);
        if(WF) Cf[(size_t)m*N + n] = v;
        if(WB) Cb[(size_t)m*N + n] = f2bf(v);
      }
    }
  }
}

// ---------------- causal depthwise conv1d (k=4) + bias + SiLU (xz bf16) -> u_bf -----
__global__ __launch_bounds__(256) void conv1d_silu_kernel(const unsigned short* __restrict__ xz,
                                                          const float* __restrict__ cw,
                                                          const float* __restrict__ cb,
                                                          unsigned short* __restrict__ ub){
  int g = blockIdx.x*256 + threadIdx.x;   // b*2^21 + l*512 + d
  int d = g & 511;
  int l = (g>>9) & 4095;
  int b = g >> 21;
  const unsigned short* up = xz + (size_t)b*LSEQ*1024 + d;
  float accv = cb[d];
  #pragma unroll
  for(int k=0;k<4;k++){
    int ls = l-3+k;
    float vv = (ls>=0) ? bf2f(up[(size_t)ls*1024]) : 0.f;
    accv += vv * cw[d*4+k];
  }
  ub[(size_t)g] = f2bf(silu_f(accv));
}

// ================= chunked selective scan (dt,u bf16; xdbl fp32 [B|C] 32/row) =======
__global__ __launch_bounds__(256) void scan_pass1(const unsigned short* __restrict__ dt,
                                                  const unsigned short* __restrict__ u,
                                                  const float* __restrict__ xdbl,
                                                  const float* __restrict__ A_log,
                                                  float* __restrict__ Ap,
                                                  float* __restrict__ Ep){
  int G = blockIdx.x*256 + threadIdx.x;
  int s  = G & 15;
  int dl = (G>>4)&3;
  int c  = (G>>6)&63;
  int dh = (G>>12)&127;
  int b  = G>>19;
  int d  = dh*4 + dl;
  float a = -__expf(A_log[d*16+s]);
  const unsigned short* dtp = dt + (size_t)b*LSEQ*512 + d;
  const unsigned short* up  = u  + (size_t)b*LSEQ*512 + d;
  const float* xb  = xdbl + (size_t)b*LSEQ*32;
  int t0 = c*CHL;
  float aprod = 1.f, h = 0.f;
  for(int tt=0;tt<CHL;tt++){
    int t = t0+tt;
    float dtv = bf2f(dtp[(size_t)t*512]);
    float uv  = bf2f(up[(size_t)t*512]);
    float bv  = xb[t*32 + s];
    float dA  = __expf(dtv*a);
    h = dA*h + dtv*bv*uv;
    aprod *= dA;
  }
  int idx = b*8192 + d*16 + s;       // 0..16383
  Ap[(size_t)c*16384 + idx] = aprod;
  Ep[(size_t)c*16384 + idx] = h;
}

__global__ __launch_bounds__(256) void scan_pass2(const float* __restrict__ Ap,
                                                  float* __restrict__ Ep){
  int idx = blockIdx.x*256 + threadIdx.x;   // 0..16383
  float h = 0.f;
  for(int c=0;c<NCH;c++){
    float a = Ap[(size_t)c*16384 + idx];
    float e = Ep[(size_t)c*16384 + idx];
    Ep[(size_t)c*16384 + idx] = h;
    h = a*h + e;
  }
}

__global__ __launch_bounds__(256) void scan_pass3(const unsigned short* __restrict__ dt,
                                                  const unsigned short* __restrict__ u,
                                                  const unsigned short* __restrict__ xz,
                                                  const float* __restrict__ xdbl,
                                                  const float* __restrict__ A_log,
                                                  const float* __restrict__ Ep,
                                                  const float* __restrict__ Dsk,
                                                  unsigned short* __restrict__ yb){
  int G = blockIdx.x*256 + threadIdx.x;
  int s  = G & 15;
  int dl = (G>>4)&3;
  int c  = (G>>6)&63;
  int dh = (G>>12)&127;
  int b  = G>>19;
  int d  = dh*4 + dl;
  float a = -__expf(A_log[d*16+s]);
  const unsigned short* dtp = dt + (size_t)b*LSEQ*512 + d;
  const unsigned short* up  = u  + (size_t)b*LSEQ*512 + d;
  const float* xb  = xdbl + (size_t)b*LSEQ*32;
  unsigned short* yp = yb + (size_t)b*LSEQ*512 + d;
  int idx = b*8192 + d*16 + s;
  float h = Ep[(size_t)c*16384 + idx];
  float dskv = Dsk[d];
  int t0 = c*CHL;
  for(int tt=0;tt<CHL;tt++){
    int t = t0+tt;
    float dtv = bf2f(dtp[(size_t)t*512]);
    float uv  = bf2f(up[(size_t)t*512]);
    float bv  = xb[t*32 + s];
    float cv  = xb[t*32 + 16 + s];
    float dA  = __expf(dtv*a);
    h = dA*h + dtv*bv*uv;
    float pp = h*cv;
    pp += __shfl_xor(pp,1);
    pp += __shfl_xor(pp,2);
    pp += __shfl_xor(pp,4);
    pp += __shfl_xor(pp,8);
    if(s==0){
      float z = bf2f(xz[(size_t)(b*LSEQ + t)*1024 + 512 + d]);
      yp[(size_t)t*512] = f2bf((pp + uv*dskv) * silu_f(z));
    }
  }
}

// ================= conv3d via bf16 MFMA implicit GEMM (9-way tap split) =============
// single-writer padded fill: every byte of xt written exactly once per call.
__global__ __launch_bounds__(256) void xt_fill(const float* __restrict__ x,
                                               unsigned short* __restrict__ xt){
  int bid = blockIdx.x;
  int b = bid / 324; int r = bid - b*324;
  int zz = r / 18, yy = r - zz*18;
  bool inner = (zz>=1 && zz<=16 && yy>=1 && yy<=16);
  unsigned short* xd = xt + (size_t)((b*18 + zz)*18 + yy)*18*256;
  const float* xs = x + (size_t)b*256*4096 + (zz-1)*256 + (yy-1)*16;
  int t = threadIdx.x;
  for(int u = t; u < 576; u += 256){
    int xpos = u >> 5;           // 0..17
    int ci0 = (u & 31) * 8;
    uint4 val = make_uint4(0,0,0,0);
    if(inner && xpos>=1 && xpos<=16){
      int xi = xpos-1;
      unsigned pk[4];
      #pragma unroll
      for(int j=0;j<4;j++){
        unsigned short lo = f2bf(xs[(size_t)(ci0+2*j  )*4096 + xi]);
        unsigned short hi = f2bf(xs[(size_t)(ci0+2*j+1)*4096 + xi]);
        pk[j] = (unsigned)lo | ((unsigned)hi << 16);
      }
      val = make_uint4(pk[0],pk[1],pk[2],pk[3]);
    }
    *(uint4*)(xd + (size_t)u*8) = val;
  }
}

__global__ __launch_bounds__(256) void wt_conv(const float* __restrict__ w3,
                                               unsigned short* __restrict__ wt){
  int idx = blockIdx.x*256 + threadIdx.x;   // 0..1,769,471
  int ci = idx & 255; int r = idx >> 8;     // 0..6911
  int tap = r % 27, co = r / 27;
  wt[idx] = f2bf(w3[(size_t)co*6912 + ci*27 + tap]);
}

// 576 blocks = 9 tap-groups (dz,dy) x 64 m-tiles (128m x 256co); 3 taps (dx) each.
// 8 waves = 4(co-64) x 2(m-64); wave tile 64co x 64m: per c8-step 8 loads : 16 MFMAs
// (32 FLOP/B, 1.5x R12). A(wt) read once per m-tile -> 226 MB total (4x less than
// R12); B(xt) ~57 MB. Targets the per-CU outstanding-miss cap by cutting traffic.
// bf16 partials, single writer per element: g<8 -> p07 plane g, g==8 -> p8.
__global__ __launch_bounds__(512) void conv3d_part(const unsigned short* __restrict__ xt,
                                                   const unsigned short* __restrict__ wt,
                                                   unsigned short* __restrict__ p07,
                                                   unsigned short* __restrict__ p8){
  int bid = blockIdx.x;
  int g = bid / 64;             // 0..8 = (dz+1)*3 + (dy+1)
  int mtile = bid - g*64;       // 0..63 (128 m each)
  int gz = g/3, gy = g - gz*3;  // gz=dz+1, gy=dy+1
  int tid = threadIdx.x;
  int l  = tid & 63;
  int w  = tid >> 6;            // 8 waves
  int cg = w & 3;               // co-64 group
  int mg = w >> 2;              // m-64 group
  int lr = l & 15;
  int lk = l >> 4;

  const unsigned short* abase = wt + (size_t)(cg*64 + lr)*6912 + (g*3)*256 + lk*8;
  int m0 = mtile*128 + mg*64 + lr;
  int b = m0 >> 12, sp0 = m0 & 4095;
  int z = sp0 >> 8, y = (sp0 >> 4) & 15, x = sp0 & 15;
  // padded coords: zz = z+gz, yy = y+gy, xx = x+1+dx; y base multiple of 4 -> +fm*16 m
  // = +fm y-rows stays in-plane (y+3 <= 15).
  const unsigned short* bbase = xt
      + (size_t)(((b*18 + z + gz)*18 + (y + gy))*18 + (x+1))*256 + lk*8;

  f32x4 acc[4][4] = {};
  for(int t=0; t<3; ++t){       // dx = t-1
    const unsigned short* ap = abase + t*256;
    const unsigned short* bp = bbase + (t-1)*256;
    #pragma unroll
    for(int c8=0; c8<8; ++c8){
      short8 a0 = *(const short8*)(ap);
      short8 a1 = *(const short8*)(ap + 16*6912);
      short8 a2 = *(const short8*)(ap + 32*6912);
      short8 a3 = *(const short8*)(ap + 48*6912);
      short8 b0 = *(const short8*)(bp);
      short8 b1 = *(const short8*)(bp + 4608);     // +16 m = +1 y-row
      short8 b2 = *(const short8*)(bp + 2*4608);
      short8 b3 = *(const short8*)(bp + 3*4608);
      acc[0][0] = __builtin_amdgcn_mfma_f32_16x16x32_bf16(a0, b0, acc[0][0], 0,0,0);
      acc[0][1] = __builtin_amdgcn_mfma_f32_16x16x32_bf16(a0, b1, acc[0][1], 0,0,0);
      acc[0][2] = __builtin_amdgcn_mfma_f32_16x16x32_bf16(a0, b2, acc[0][2], 0,0,0);
      acc[0][3] = __builtin_amdgcn_mfma_f32_16x16x32_bf16(a0, b3, acc[0][3], 0,0,0);
      acc[1][0] = __builtin_amdgcn_mfma_f32_16x16x32_bf16(a1, b0, acc[1][0], 0,0,0);
      acc[1][1] = __builtin_amdgcn_mfma_f32_16x16x32_bf16(a1, b1, acc[1][1], 0,0,0);
      acc[1][2] = __builtin_amdgcn_mfma_f32_16x16x32_bf16(a1, b2, acc[1][2], 0,0,0);
      acc[1][3] = __builtin_amdgcn_mfma_f32_16x16x32_bf16(a1, b3, acc[1][3], 0,0,0);
      acc[2][0] = __builtin_amdgcn_mfma_f32_16x16x32_bf16(a2, b0, acc[2][0], 0,0,0);
      acc[2][1] = __builtin_amdgcn_mfma_f32_16x16x32_bf16(a2, b1, acc[2][1], 0,0,0);
      acc[2][2] = __builtin_amdgcn_mfma_f32_16x16x32_bf16(a2, b2, acc[2][2], 0,0,0);
      acc[2][3] = __builtin_amdgcn_mfma_f32_16x16x32_bf16(a2, b3, acc[2][3], 0,0,0);
      acc[3][0] = __builtin_amdgcn_mfma_f32_16x16x32_bf16(a3, b0, acc[3][0], 0,0,0);
      acc[3][1] = __builtin_amdgcn_mfma_f32_16x16x32_bf16(a3, b1, acc[3][1], 0,0,0);
      acc[3][2] = __builtin_amdgcn_mfma_f32_16x16x32_bf16(a3, b2, acc[3][2], 0,0,0);
      acc[3][3] = __builtin_amdgcn_mfma_f32_16x16x32_bf16(a3, b3, acc[3][3], 0,0,0);
      ap += 32; bp += 32;
    }
  }
  unsigned short* pg = (g < 8) ? (p07 + (size_t)g*2097152) : p8;
  #pragma unroll
  for(int fc=0; fc<4; ++fc){
    #pragma unroll
    for(int fm=0; fm<4; ++fm){
      int m = mtile*128 + mg*64 + fm*16 + lr;
      int bb = m >> 12, sp = m & 4095;
      #pragma unroll
      for(int r=0; r<4; ++r){
        int co = cg*64 + fc*16 + 4*lk + r;
        pg[((size_t)(bb*256 + co))*4096 + sp] = f2bf(acc[fc][fm][r]);
      }
    }
  }
}

// combine: out = hb + softplus(scale)*prelu(sum of 9 bf16 partials); 512 blocks=(b,co)
__global__ __launch_bounds__(256) void conv3d_combine(const unsigned short* __restrict__ p07,
                                                      const unsigned short* __restrict__ p8,
                                                      const unsigned short* __restrict__ hb,
                                                      const float* __restrict__ prelu_a,
                                                      const float* __restrict__ scale,
                                                      float* __restrict__ out){
  int bc = blockIdx.x;          // b*256 + co
  int b = bc >> 8, co = bc & 255;
  float spv = sp_f(scale[0]);
  float pa = prelu_a[0];
  #pragma unroll 4
  for(int it=0; it<16; ++it){
    int sp = it*256 + threadIdx.x;
    size_t o = (size_t)bc*4096 + sp;
    float v = bf2f(p8[o]);
    #pragma unroll
    for(int g=0; g<8; ++g) v += bf2f(p07[(size_t)g*2097152 + o]);
    float pr = v > 0.f ? v : pa*v;
    int m = b*4096 + sp;
    out[o] = bf2f(hb[(size_t)m*256 + co]) + spv*pr;
  }
}

extern "C" void kernel_launch(void* const* d_in, const int* in_sizes, int n_in,
                              void* d_out, int out_size, void* d_ws, size_t ws_size,
                              hipStream_t stream) {
  const float* x         = (const float*)d_in[0];
  const float* ln_w      = (const float*)d_in[1];
  const float* ln_b      = (const float*)d_in[2];
  const float* in_proj_w = (const float*)d_in[3];
  const float* conv_w    = (const float*)d_in[4];
  const float* conv_b    = (const float*)d_in[5];
  const float* x_proj_w  = (const float*)d_in[6];
  const float* dt_proj_w = (const float*)d_in[7];
  const float* dt_proj_b = (const float*)d_in[8];
  const float* A_log     = (const float*)d_in[9];
  const float* D_skip    = (const float*)d_in[10];
  const float* out_proj_w= (const float*)d_in[11];
  const float* conv3d_w  = (const float*)d_in[12];
  const float* prelu_a   = (const float*)d_in[13];
  const float* scale     = (const float*)d_in[14];
  float* out = (float*)d_out;

  // workspace layout (float offsets). conv3d partials alias the mamba region that is
  // dead at conv time and fully rewritten (before any read) next call.
  float* ws   = (float*)d_ws;
  float* Ap   = ws;                               // 1,048,576 fl
  float* Ep   = Ap + 1048576;                     // 1,048,576 fl
  unsigned short* xz_bf = (unsigned short*)(Ep + 1048576);     // 8,388,608 bf16
  unsigned short* u_bf  = xz_bf + 8388608;        // 4,194,304 bf16
  float* xdbl = (float*)(u_bf + 4194304);         // 262,144 fl
  unsigned short* dt_bf = (unsigned short*)(xdbl + 262144);    // 4,194,304 bf16
  unsigned short* h_bf  = dt_bf + 4194304;        // 2,097,152 bf16 (LIVE at conv time)
  unsigned short* y_bf  = h_bf + 2097152;         // 4,194,304 bf16 (dead after out_proj)
  unsigned short* inw_bf   = y_bf + 4194304;      // 524,288 bf16
  unsigned short* ow_bf    = inw_bf + 524288;     // 262,144 bf16
  unsigned short* xpwbc_bf = ow_bf + 262144;      // 32,768 bf16
  unsigned short* wdt_bf   = xpwbc_bf + 32768;    // 524,288 bf16
  const size_t base_floats = 14565376;            // 58,261,504 bytes
  // partial planes 0..7: 16,777,216 shorts, fits in xz..dt region (17,301,504 shorts)
  unsigned short* p07 = xz_bf;
  unsigned short* p8  = y_bf;                     // plane 8 (2,097,152 <= 4,194,304)
  // xt/wt at dedicated tail (ws >= 77,070,336 B established by rounds 1-4 layouts)
  unsigned short* xt = (unsigned short*)(ws + base_floats);
  unsigned short* wt = xt + 2985984;

  // ---- weight prep (bf16) ----
  cvt_bf<<<2048, 256, 0, stream>>>(in_proj_w, inw_bf, 524288);
  cvt_bf<<<1024, 256, 0, stream>>>(out_proj_w, ow_bf, 262144);
  cvt_bf<<<64, 256, 0, stream>>>(x_proj_w + 16*512, xpwbc_bf, 16384);
  cvt_bf<<<64, 256, 0, stream>>>(x_proj_w + 48*512 + 16*512, xpwbc_bf + 16384, 16384);
  wdt_kernel<<<2048, 256, 0, stream>>>(dt_proj_w, x_proj_w, wdt_bf);

  ln_kernel<<<LSEQ*2, 64, 0, stream>>>(x, ln_w, ln_b, h_bf);

  for(int dep=0; dep<2; dep++){
    const unsigned short* inw = inw_bf   + (size_t)dep*262144;
    const unsigned short* oww = ow_bf    + (size_t)dep*131072;
    const unsigned short* xpw = xpwbc_bf + (size_t)dep*16384;
    const unsigned short* wdt = wdt_bf   + (size_t)dep*262144;
    const float* cw   = conv_w    + (size_t)dep*512*4;
    const float* cb   = conv_b    + (size_t)dep*512;
    const float* dtb  = dt_proj_b + (size_t)dep*512;
    const float* Alg  = A_log     + (size_t)dep*512*16;
    const float* Dsk  = D_skip    + (size_t)dep*512;

    // in_proj: xz_bf[8192,1024] = h_bf @ inw^T   (512 blocks)
    gemm_mfma<4,4,2,2,0,0,1><<<dim3(8,64), 256, 0, stream>>>(
        h_bf, inw, nullptr, nullptr, xz_bf, 8192, 1024, 256);
    conv1d_silu_kernel<<<16384, 256, 0, stream>>>(xz_bf, cw, cb, u_bf);
    // x_proj B,C: xdbl[8192,32] = u_bf @ xpw_bc^T  (256 blocks)
    gemm_mfma<1,1,2,2,0,1,0><<<dim3(1,256), 256, 0, stream>>>(
        u_bf, xpw, nullptr, xdbl, nullptr, 8192, 32, 512);
    // dt (folded): dt_bf[8192,512] = softplus(u_bf @ wdt^T + dtb)  (512 blocks)
    gemm_mfma<2,4,2,2,1,0,1><<<dim3(4,128), 256, 0, stream>>>(
        u_bf, wdt, dtb, nullptr, dt_bf, 8192, 512, 512);

    scan_pass1<<<4096, 256, 0, stream>>>(dt_bf, u_bf, xdbl, Alg, Ap, Ep);
    scan_pass2<<<64, 256, 0, stream>>>(Ap, Ep);
    scan_pass3<<<4096, 256, 0, stream>>>(dt_bf, u_bf, xz_bf, xdbl, Alg, Ep, Dsk, y_bf);

    // out_proj: h_bf[8192,256] = y_bf @ ow^T  (512 blocks)
    gemm_mfma<1,4,2,2,0,0,1><<<dim3(2,256), 256, 0, stream>>>(
        y_bf, oww, nullptr, nullptr, h_bf, 8192, 256, 512);
  }

  // conv3d: prep + 9-way tap-split partials (128m x 256co blocks) + combine epilogue
  xt_fill<<<648, 256, 0, stream>>>(x, xt);
  wt_conv<<<6912, 256, 0, stream>>>(conv3d_w, wt);
  conv3d_part<<<576, 512, 0, stream>>>(xt, wt, p07, p8);
  conv3d_combine<<<512, 256, 0, stream>>>(p07, p8, h_bf, prelu_a, scale, out);
}

// Round 14
// 646.370 us; speedup vs baseline: 1.0991x; 1.0355x over previous
//
#include <hip/hip_runtime.h>
#include <math.h>

#define LSEQ 4096
#define DIMC 256
#define DI   512
#define NCH  64     // chunks over L
#define CHL  64     // chunk length

typedef short short8 __attribute__((ext_vector_type(8)));
typedef float f32x4 __attribute__((ext_vector_type(4)));

__device__ __forceinline__ float sp_f(float v){ return fmaxf(v,0.f) + log1pf(__expf(-fabsf(v))); }
__device__ __forceinline__ float silu_f(float v){ return v/(1.f+__expf(-v)); }
__device__ __forceinline__ unsigned short f2bf(float f){
  unsigned u = __builtin_bit_cast(unsigned, f);
  unsigned r = (u + 0x7FFFu + ((u>>16)&1u)) >> 16;
  return (unsigned short)r;
}
__device__ __forceinline__ float bf2f(unsigned short us){
  unsigned u = ((unsigned)us)<<16;
  return __builtin_bit_cast(float, u);
}

// ---------------- LayerNorm: x (B,C,L) -> h_bf (B*L, C) bf16 -------------------------
__global__ __launch_bounds__(64) void ln_kernel(const float* __restrict__ x,
                                                const float* __restrict__ w,
                                                const float* __restrict__ bias,
                                                unsigned short* __restrict__ hb){
  int row = blockIdx.x;            // b*L + l
  int b = row >> 12, l = row & 4095;
  int i = threadIdx.x;             // 0..63
  const float* xb = x + (size_t)b*DIMC*LSEQ + l;
  float v[4]; float s=0.f, sq=0.f;
  #pragma unroll
  for(int j=0;j<4;j++){ float t = xb[(size_t)(j*64+i)*LSEQ]; v[j]=t; s+=t; sq+=t*t; }
  #pragma unroll
  for(int o=1;o<64;o<<=1){ s += __shfl_xor(s,o); sq += __shfl_xor(sq,o); }
  float mu = s*(1.f/256.f);
  float var = sq*(1.f/256.f) - mu*mu;
  float rs = rsqrtf(var + 1e-5f);
  unsigned short* hr = hb + (size_t)row*DIMC;
  #pragma unroll
  for(int j=0;j<4;j++){ int c=j*64+i; hr[c] = f2bf((v[j]-mu)*rs*w[c] + bias[c]); }
}

// ---------------- generic bf16 copy of weights ---------------------------------------
__global__ __launch_bounds__(256) void cvt_bf(const float* __restrict__ src,
                                              unsigned short* __restrict__ dst, int n){
  int i = blockIdx.x*256 + threadIdx.x;
  if(i < n) dst[i] = f2bf(src[i]);
}

// ---------------- W_dt[dep][n][k] = sum_j dtw[dep][n][j] * xpw[dep][j][k] ------------
__global__ __launch_bounds__(256) void wdt_kernel(const float* __restrict__ dtw,
                                                  const float* __restrict__ xpw,
                                                  unsigned short* __restrict__ wdt){
  int idx = blockIdx.x*256 + threadIdx.x;   // 0..524287
  int dep = idx >> 18;
  int r = idx & 262143;
  int n = r >> 9, k = r & 511;
  const float* dw = dtw + (size_t)dep*512*16 + n*16;
  const float* xp = xpw + (size_t)dep*48*512 + k;
  float acc = 0.f;
  #pragma unroll
  for(int j=0;j<16;j++) acc += dw[j] * xp[(size_t)j*512];
  wdt[idx] = f2bf(acc);
}

// ---------------- small all-global bf16 MFMA GEMM (kept for x_proj, N=32) ------------
template<int FM,int FN,int WM,int WN,int EPI,int WF,int WB>
__global__ __launch_bounds__(WM*WN*64) void gemm_mfma(
    const unsigned short* __restrict__ A,
    const unsigned short* __restrict__ W,
    const float* __restrict__ bias,
    float* __restrict__ Cf,
    unsigned short* __restrict__ Cb,
    int M, int N, int K){
  int tid = threadIdx.x;
  int l = tid & 63, w = tid >> 6;
  int w_n = w % WN, w_m = w / WN;
  int lr = l & 15, lk = l >> 4;
  int nb = blockIdx.x * (WN*FN*16) + w_n*(FN*16);
  int mb = blockIdx.y * (WM*FM*16) + w_m*(FM*16);
  const unsigned short* ap[FN];
  const unsigned short* bp[FM];
  #pragma unroll
  for(int i=0;i<FN;i++) ap[i] = W + (size_t)(nb + i*16 + lr)*K + lk*8;
  #pragma unroll
  for(int i=0;i<FM;i++) bp[i] = A + (size_t)(mb + i*16 + lr)*K + lk*8;
  f32x4 acc[FN][FM] = {};
  for(int k0=0;k0<K;k0+=32){
    short8 av[FN], bv[FM];
    #pragma unroll
    for(int i=0;i<FN;i++) av[i] = *(const short8*)(ap[i]);
    #pragma unroll
    for(int i=0;i<FM;i++) bv[i] = *(const short8*)(bp[i]);
    #pragma unroll
    for(int i=0;i<FN;i++)
      #pragma unroll
      for(int j=0;j<FM;j++)
        acc[i][j] = __builtin_amdgcn_mfma_f32_16x16x32_bf16(av[i], bv[j], acc[i][j], 0,0,0);
    #pragma unroll
    for(int i=0;i<FN;i++) ap[i] += 32;
    #pragma unroll
    for(int i=0;i<FM;i++) bp[i] += 32;
  }
  #pragma unroll
  for(int i=0;i<FN;i++){
    #pragma unroll
    for(int j=0;j<FM;j++){
      int m = mb + j*16 + lr;
      #pragma unroll
      for(int r=0;r<4;r++){
        int n = nb + i*16 + 4*lk + r;
        float v = acc[i][j][r];
        if(EPI==1) v = sp_f(v + bias[n]);
        if(WF) Cf[(size_t)m*N + n] = v;
        if(WB) Cb[(size_t)m*N + n] = f2bf(v);
      }
    }
  }
}

// ---------------- LDS-staged bf16 MFMA GEMM: D[n][m] = W[n,:]·A[m,:] -----------------
// BM=128 (m), BN=64 (n), BK=64; 256 thr = 4 waves (2n x 2m), wave tile 32n x 64m.
// Coalesced global->LDS staging (per-thread 16B contiguous chunks), padded rows
// (72 shorts = 144B, mult of 16B: ds_read_b128 aligned, <=2-way bank alias = free).
template<int EPI,int WF,int WB>
__global__ __launch_bounds__(256) void gemm_lds(
    const unsigned short* __restrict__ A,   // M x K (m rows, B-operand)
    const unsigned short* __restrict__ W,   // N x K (n rows, A-operand)
    const float* __restrict__ bias,
    float* __restrict__ Cf,
    unsigned short* __restrict__ Cb,
    int M, int N, int K){
  __shared__ unsigned short Wt[64][72];
  __shared__ unsigned short Xt[128][72];
  int tid = threadIdx.x;
  int l = tid & 63, w = tid >> 6;
  int lr = l & 15, lk = l >> 4;
  int w_n = w & 1, w_m = w >> 1;
  int nb = blockIdx.x * 64;
  int mb = blockIdx.y * 128;
  int srow = tid >> 3, sc8 = tid & 7;       // staging: 8 threads/row, 16B each
  f32x4 acc[2][4] = {};
  for(int k0 = 0; k0 < K; k0 += 64){
    __syncthreads();
    #pragma unroll
    for(int q=0;q<2;q++){
      int row = q*32 + srow;
      *(uint4*)&Wt[row][sc8*8] = *(const uint4*)(W + (size_t)(nb+row)*K + k0 + sc8*8);
    }
    #pragma unroll
    for(int q=0;q<4;q++){
      int row = q*32 + srow;
      *(uint4*)&Xt[row][sc8*8] = *(const uint4*)(A + (size_t)(mb+row)*K + k0 + sc8*8);
    }
    __syncthreads();
    #pragma unroll
    for(int kk=0;kk<2;kk++){
      short8 af[2], bf[4];
      #pragma unroll
      for(int i=0;i<2;i++) af[i] = *(const short8*)&Wt[w_n*32+i*16+lr][kk*32+lk*8];
      #pragma unroll
      for(int j=0;j<4;j++) bf[j] = *(const short8*)&Xt[w_m*64+j*16+lr][kk*32+lk*8];
      #pragma unroll
      for(int i=0;i<2;i++)
        #pragma unroll
        for(int j=0;j<4;j++)
          acc[i][j] = __builtin_amdgcn_mfma_f32_16x16x32_bf16(af[i], bf[j], acc[i][j], 0,0,0);
    }
  }
  #pragma unroll
  for(int i=0;i<2;i++){
    #pragma unroll
    for(int j=0;j<4;j++){
      int m = mb + w_m*64 + j*16 + lr;
      #pragma unroll
      for(int r=0;r<4;r++){
        int n = nb + w_n*32 + i*16 + 4*lk + r;
        float v = acc[i][j][r];
        if(EPI==1) v = sp_f(v + bias[n]);
        if(WF) Cf[(size_t)m*N + n] = v;
        if(WB) Cb[(size_t)m*N + n] = f2bf(v);
      }
    }
  }
}

// ---------------- causal depthwise conv1d (k=4) + bias + SiLU (xz bf16) -> u_bf -----
__global__ __launch_bounds__(256) void conv1d_silu_kernel(const unsigned short* __restrict__ xz,
                                                          const float* __restrict__ cw,
                                                          const float* __restrict__ cb,
                                                          unsigned short* __restrict__ ub){
  int g = blockIdx.x*256 + threadIdx.x;   // b*2^21 + l*512 + d
  int d = g & 511;
  int l = (g>>9) & 4095;
  int b = g >> 21;
  const unsigned short* up = xz + (size_t)b*LSEQ*1024 + d;
  float accv = cb[d];
  #pragma unroll
  for(int k=0;k<4;k++){
    int ls = l-3+k;
    float vv = (ls>=0) ? bf2f(up[(size_t)ls*1024]) : 0.f;
    accv += vv * cw[d*4+k];
  }
  ub[(size_t)g] = f2bf(silu_f(accv));
}

// ================= chunked selective scan (dt,u bf16; xdbl fp32 [B|C] 32/row) =======
__global__ __launch_bounds__(256) void scan_pass1(const unsigned short* __restrict__ dt,
                                                  const unsigned short* __restrict__ u,
                                                  const float* __restrict__ xdbl,
                                                  const float* __restrict__ A_log,
                                                  float* __restrict__ Ap,
                                                  float* __restrict__ Ep){
  int G = blockIdx.x*256 + threadIdx.x;
  int s  = G & 15;
  int dl = (G>>4)&3;
  int c  = (G>>6)&63;
  int dh = (G>>12)&127;
  int b  = G>>19;
  int d  = dh*4 + dl;
  float a = -__expf(A_log[d*16+s]);
  const unsigned short* dtp = dt + (size_t)b*LSEQ*512 + d;
  const unsigned short* up  = u  + (size_t)b*LSEQ*512 + d;
  const float* xb  = xdbl + (size_t)b*LSEQ*32;
  int t0 = c*CHL;
  float aprod = 1.f, h = 0.f;
  for(int tt=0;tt<CHL;tt++){
    int t = t0+tt;
    float dtv = bf2f(dtp[(size_t)t*512]);
    float uv  = bf2f(up[(size_t)t*512]);
    float bv  = xb[t*32 + s];
    float dA  = __expf(dtv*a);
    h = dA*h + dtv*bv*uv;
    aprod *= dA;
  }
  int idx = b*8192 + d*16 + s;       // 0..16383
  Ap[(size_t)c*16384 + idx] = aprod;
  Ep[(size_t)c*16384 + idx] = h;
}

__global__ __launch_bounds__(256) void scan_pass2(const float* __restrict__ Ap,
                                                  float* __restrict__ Ep){
  int idx = blockIdx.x*256 + threadIdx.x;   // 0..16383
  float h = 0.f;
  for(int c=0;c<NCH;c++){
    float a = Ap[(size_t)c*16384 + idx];
    float e = Ep[(size_t)c*16384 + idx];
    Ep[(size_t)c*16384 + idx] = h;
    h = a*h + e;
  }
}

__global__ __launch_bounds__(256) void scan_pass3(const unsigned short* __restrict__ dt,
                                                  const unsigned short* __restrict__ u,
                                                  const unsigned short* __restrict__ xz,
                                                  const float* __restrict__ xdbl,
                                                  const float* __restrict__ A_log,
                                                  const float* __restrict__ Ep,
                                                  const float* __restrict__ Dsk,
                                                  unsigned short* __restrict__ yb){
  int G = blockIdx.x*256 + threadIdx.x;
  int s  = G & 15;
  int dl = (G>>4)&3;
  int c  = (G>>6)&63;
  int dh = (G>>12)&127;
  int b  = G>>19;
  int d  = dh*4 + dl;
  float a = -__expf(A_log[d*16+s]);
  const unsigned short* dtp = dt + (size_t)b*LSEQ*512 + d;
  const unsigned short* up  = u  + (size_t)b*LSEQ*512 + d;
  const float* xb  = xdbl + (size_t)b*LSEQ*32;
  unsigned short* yp = yb + (size_t)b*LSEQ*512 + d;
  int idx = b*8192 + d*16 + s;
  float h = Ep[(size_t)c*16384 + idx];
  float dskv = Dsk[d];
  int t0 = c*CHL;
  for(int tt=0;tt<CHL;tt++){
    int t = t0+tt;
    float dtv = bf2f(dtp[(size_t)t*512]);
    float uv  = bf2f(up[(size_t)t*512]);
    float bv  = xb[t*32 + s];
    float cv  = xb[t*32 + 16 + s];
    float dA  = __expf(dtv*a);
    h = dA*h + dtv*bv*uv;
    float pp = h*cv;
    pp += __shfl_xor(pp,1);
    pp += __shfl_xor(pp,2);
    pp += __shfl_xor(pp,4);
    pp += __shfl_xor(pp,8);
    if(s==0){
      float z = bf2f(xz[(size_t)(b*LSEQ + t)*1024 + 512 + d]);
      yp[(size_t)t*512] = f2bf((pp + uv*dskv) * silu_f(z));
    }
  }
}

// ================= conv3d via LDS-staged bf16 MFMA implicit GEMM ====================
// single-writer padded fill: every byte of xt written exactly once per call.
__global__ __launch_bounds__(256) void xt_fill(const float* __restrict__ x,
                                               unsigned short* __restrict__ xt){
  int bid = blockIdx.x;
  int b = bid / 324; int r = bid - b*324;
  int zz = r / 18, yy = r - zz*18;
  bool inner = (zz>=1 && zz<=16 && yy>=1 && yy<=16);
  unsigned short* xd = xt + (size_t)((b*18 + zz)*18 + yy)*18*256;
  const float* xs = x + (size_t)b*256*4096 + (zz-1)*256 + (yy-1)*16;
  int t = threadIdx.x;
  for(int u = t; u < 576; u += 256){
    int xpos = u >> 5;           // 0..17
    int ci0 = (u & 31) * 8;
    uint4 val = make_uint4(0,0,0,0);
    if(inner && xpos>=1 && xpos<=16){
      int xi = xpos-1;
      unsigned pk[4];
      #pragma unroll
      for(int j=0;j<4;j++){
        unsigned short lo = f2bf(xs[(size_t)(ci0+2*j  )*4096 + xi]);
        unsigned short hi = f2bf(xs[(size_t)(ci0+2*j+1)*4096 + xi]);
        pk[j] = (unsigned)lo | ((unsigned)hi << 16);
      }
      val = make_uint4(pk[0],pk[1],pk[2],pk[3]);
    }
    *(uint4*)(xd + (size_t)u*8) = val;
  }
}

__global__ __launch_bounds__(256) void wt_conv(const float* __restrict__ w3,
                                               unsigned short* __restrict__ wt){
  int idx = blockIdx.x*256 + threadIdx.x;   // 0..1,769,471
  int ci = idx & 255; int r = idx >> 8;     // 0..6911
  int tap = r % 27, co = r / 27;
  wt[idx] = f2bf(w3[(size_t)co*6912 + ci*27 + tap]);
}

// 256 blocks = 64 m-tiles(128) x 4 co-tiles(64). Same LDS-GEMM structure as gemm_lds;
// K = 27 taps x 256 ci, staged 64-ci chunks; fused prelu+skip epilogue writes out.
__global__ __launch_bounds__(256) void conv3d_lds(const unsigned short* __restrict__ xt,
                                                  const unsigned short* __restrict__ wt,
                                                  const unsigned short* __restrict__ hb,
                                                  const float* __restrict__ prelu_a,
                                                  const float* __restrict__ scale,
                                                  float* __restrict__ out){
  __shared__ unsigned short Wt2[64][72];
  __shared__ unsigned short Xt2[128][72];
  int bid = blockIdx.x;
  int nb = (bid & 3)*64;        // co tile
  int mb = (bid >> 2)*128;      // m tile
  int tid = threadIdx.x;
  int l = tid & 63, w = tid >> 6;
  int lr = l & 15, lk = l >> 4;
  int w_n = w & 1, w_m = w >> 1;
  int srow = tid >> 3, sc8 = tid & 7;
  // per-thread X staging bases (tap-0 padded offsets) for the 4 row-chunks
  size_t xbase[4];
  #pragma unroll
  for(int q=0;q<4;q++){
    int m = mb + q*32 + srow;
    int b = m >> 12, sp = m & 4095;
    int z = sp >> 8, y = (sp >> 4) & 15, x = sp & 15;
    xbase[q] = (size_t)(((b*18 + z+1)*18 + (y+1))*18 + (x+1))*256;
  }
  const unsigned short* wrow0 = wt + (size_t)(nb + srow)*6912 + sc8*8;
  const unsigned short* wrow1 = wt + (size_t)(nb + 32 + srow)*6912 + sc8*8;

  f32x4 acc[2][4] = {};
  for(int step=0; step<108; ++step){
    int tap = step >> 2, cic = step & 3;
    int gz = tap/9; int rm = tap - gz*9; int gy = rm/3, gx = rm - gy*3;
    int toff = ((gz-1)*324 + (gy-1)*18 + (gx-1))*256;
    int kco = tap*256 + cic*64;
    __syncthreads();
    *(uint4*)&Wt2[srow   ][sc8*8] = *(const uint4*)(wrow0 + kco);
    *(uint4*)&Wt2[32+srow][sc8*8] = *(const uint4*)(wrow1 + kco);
    #pragma unroll
    for(int q=0;q<4;q++)
      *(uint4*)&Xt2[q*32+srow][sc8*8] = *(const uint4*)(xt + xbase[q] + toff + cic*64 + sc8*8);
    __syncthreads();
    #pragma unroll
    for(int kk=0;kk<2;kk++){
      short8 af[2], bf[4];
      #pragma unroll
      for(int i=0;i<2;i++) af[i] = *(const short8*)&Wt2[w_n*32+i*16+lr][kk*32+lk*8];
      #pragma unroll
      for(int j=0;j<4;j++) bf[j] = *(const short8*)&Xt2[w_m*64+j*16+lr][kk*32+lk*8];
      #pragma unroll
      for(int i=0;i<2;i++)
        #pragma unroll
        for(int j=0;j<4;j++)
          acc[i][j] = __builtin_amdgcn_mfma_f32_16x16x32_bf16(af[i], bf[j], acc[i][j], 0,0,0);
    }
  }
  float spv = sp_f(scale[0]);
  float pa = prelu_a[0];
  #pragma unroll
  for(int i=0;i<2;i++){
    #pragma unroll
    for(int j=0;j<4;j++){
      int m = mb + w_m*64 + j*16 + lr;
      int bb = m >> 12, sp = m & 4095;
      #pragma unroll
      for(int r=0;r<4;r++){
        int co = nb + w_n*32 + i*16 + 4*lk + r;
        float cval = acc[i][j][r];
        float pr = cval > 0.f ? cval : pa*cval;
        out[((size_t)(bb*256 + co))*4096 + sp] = bf2f(hb[(size_t)m*256 + co]) + spv*pr;
      }
    }
  }
}

extern "C" void kernel_launch(void* const* d_in, const int* in_sizes, int n_in,
                              void* d_out, int out_size, void* d_ws, size_t ws_size,
                              hipStream_t stream) {
  const float* x         = (const float*)d_in[0];
  const float* ln_w      = (const float*)d_in[1];
  const float* ln_b      = (const float*)d_in[2];
  const float* in_proj_w = (const float*)d_in[3];
  const float* conv_w    = (const float*)d_in[4];
  const float* conv_b    = (const float*)d_in[5];
  const float* x_proj_w  = (const float*)d_in[6];
  const float* dt_proj_w = (const float*)d_in[7];
  const float* dt_proj_b = (const float*)d_in[8];
  const float* A_log     = (const float*)d_in[9];
  const float* D_skip    = (const float*)d_in[10];
  const float* out_proj_w= (const float*)d_in[11];
  const float* conv3d_w  = (const float*)d_in[12];
  const float* prelu_a   = (const float*)d_in[13];
  const float* scale     = (const float*)d_in[14];
  float* out = (float*)d_out;

  // workspace layout (float offsets) — one producer per phase, no partials anymore.
  float* ws   = (float*)d_ws;
  float* Ap   = ws;                               // 1,048,576 fl
  float* Ep   = Ap + 1048576;                     // 1,048,576 fl
  unsigned short* xz_bf = (unsigned short*)(Ep + 1048576);     // 8,388,608 bf16
  unsigned short* u_bf  = xz_bf + 8388608;        // 4,194,304 bf16
  float* xdbl = (float*)(u_bf + 4194304);         // 262,144 fl
  unsigned short* dt_bf = (unsigned short*)(xdbl + 262144);    // 4,194,304 bf16
  unsigned short* h_bf  = dt_bf + 4194304;        // 2,097,152 bf16 (LIVE at conv time)
  unsigned short* y_bf  = h_bf + 2097152;         // 4,194,304 bf16
  unsigned short* inw_bf   = y_bf + 4194304;      // 524,288 bf16
  unsigned short* ow_bf    = inw_bf + 524288;     // 262,144 bf16
  unsigned short* xpwbc_bf = ow_bf + 262144;      // 32,768 bf16
  unsigned short* wdt_bf   = xpwbc_bf + 32768;    // 524,288 bf16
  const size_t base_floats = 14565376;            // 58,261,504 bytes
  // xt/wt at dedicated tail (ws >= 77,070,336 B established by rounds 1-4 layouts)
  unsigned short* xt = (unsigned short*)(ws + base_floats);
  unsigned short* wt = xt + 2985984;

  // ---- weight prep (bf16) ----
  cvt_bf<<<2048, 256, 0, stream>>>(in_proj_w, inw_bf, 524288);
  cvt_bf<<<1024, 256, 0, stream>>>(out_proj_w, ow_bf, 262144);
  cvt_bf<<<64, 256, 0, stream>>>(x_proj_w + 16*512, xpwbc_bf, 16384);
  cvt_bf<<<64, 256, 0, stream>>>(x_proj_w + 48*512 + 16*512, xpwbc_bf + 16384, 16384);
  wdt_kernel<<<2048, 256, 0, stream>>>(dt_proj_w, x_proj_w, wdt_bf);

  ln_kernel<<<LSEQ*2, 64, 0, stream>>>(x, ln_w, ln_b, h_bf);

  for(int dep=0; dep<2; dep++){
    const unsigned short* inw = inw_bf   + (size_t)dep*262144;
    const unsigned short* oww = ow_bf    + (size_t)dep*131072;
    const unsigned short* xpw = xpwbc_bf + (size_t)dep*16384;
    const unsigned short* wdt = wdt_bf   + (size_t)dep*262144;
    const float* cw   = conv_w    + (size_t)dep*512*4;
    const float* cb   = conv_b    + (size_t)dep*512;
    const float* dtb  = dt_proj_b + (size_t)dep*512;
    const float* Alg  = A_log     + (size_t)dep*512*16;
    const float* Dsk  = D_skip    + (size_t)dep*512;

    // in_proj: xz_bf[8192,1024] = h_bf @ inw^T   (16 x 64 = 1024 blocks)
    gemm_lds<0,0,1><<<dim3(16,64), 256, 0, stream>>>(
        h_bf, inw, nullptr, nullptr, xz_bf, 8192, 1024, 256);
    conv1d_silu_kernel<<<16384, 256, 0, stream>>>(xz_bf, cw, cb, u_bf);
    // x_proj B,C: xdbl[8192,32] = u_bf @ xpw_bc^T  (256 blocks, all-global)
    gemm_mfma<1,1,2,2,0,1,0><<<dim3(1,256), 256, 0, stream>>>(
        u_bf, xpw, nullptr, xdbl, nullptr, 8192, 32, 512);
    // dt (folded): dt_bf[8192,512] = softplus(u_bf @ wdt^T + dtb)  (8 x 64 = 512 blocks)
    gemm_lds<1,0,1><<<dim3(8,64), 256, 0, stream>>>(
        u_bf, wdt, dtb, nullptr, dt_bf, 8192, 512, 512);

    scan_pass1<<<4096, 256, 0, stream>>>(dt_bf, u_bf, xdbl, Alg, Ap, Ep);
    scan_pass2<<<64, 256, 0, stream>>>(Ap, Ep);
    scan_pass3<<<4096, 256, 0, stream>>>(dt_bf, u_bf, xz_bf, xdbl, Alg, Ep, Dsk, y_bf);

    // out_proj: h_bf[8192,256] = y_bf @ ow^T  (4 x 64 = 256 blocks)
    gemm_lds<0,0,1><<<dim3(4,64), 256, 0, stream>>>(
        y_bf, oww, nullptr, nullptr, h_bf, 8192, 256, 512);
  }

  // conv3d: prep + LDS-staged MFMA conv with fused epilogue (direct out write)
  xt_fill<<<648, 256, 0, stream>>>(x, xt);
  wt_conv<<<6912, 256, 0, stream>>>(conv3d_w, wt);
  conv3d_lds<<<256, 256, 0, stream>>>(xt, wt, h_bf, prelu_a, scale, out);
}

// Round 15
// 542.737 us; speedup vs baseline: 1.3089x; 1.1909x over previous
//
#include <hip/hip_runtime.h>
#include <math.h>

#define LSEQ 4096
#define DIMC 256
#define DI   512
#define NCH  64     // chunks over L
#define CHL  64     // chunk length

typedef short short8 __attribute__((ext_vector_type(8)));
typedef float f32x4 __attribute__((ext_vector_type(4)));

__device__ __forceinline__ float sp_f(float v){ return fmaxf(v,0.f) + log1pf(__expf(-fabsf(v))); }
__device__ __forceinline__ float silu_f(float v){ return v/(1.f+__expf(-v)); }
__device__ __forceinline__ unsigned short f2bf(float f){
  unsigned u = __builtin_bit_cast(unsigned, f);
  unsigned r = (u + 0x7FFFu + ((u>>16)&1u)) >> 16;
  return (unsigned short)r;
}
__device__ __forceinline__ float bf2f(unsigned short us){
  unsigned u = ((unsigned)us)<<16;
  return __builtin_bit_cast(float, u);
}

// ---------------- LayerNorm: x (B,C,L) -> h_bf (B*L, C) bf16 -------------------------
__global__ __launch_bounds__(64) void ln_kernel(const float* __restrict__ x,
                                                const float* __restrict__ w,
                                                const float* __restrict__ bias,
                                                unsigned short* __restrict__ hb){
  int row = blockIdx.x;            // b*L + l
  int b = row >> 12, l = row & 4095;
  int i = threadIdx.x;             // 0..63
  const float* xb = x + (size_t)b*DIMC*LSEQ + l;
  float v[4]; float s=0.f, sq=0.f;
  #pragma unroll
  for(int j=0;j<4;j++){ float t = xb[(size_t)(j*64+i)*LSEQ]; v[j]=t; s+=t; sq+=t*t; }
  #pragma unroll
  for(int o=1;o<64;o<<=1){ s += __shfl_xor(s,o); sq += __shfl_xor(sq,o); }
  float mu = s*(1.f/256.f);
  float var = sq*(1.f/256.f) - mu*mu;
  float rs = rsqrtf(var + 1e-5f);
  unsigned short* hr = hb + (size_t)row*DIMC;
  #pragma unroll
  for(int j=0;j<4;j++){ int c=j*64+i; hr[c] = f2bf((v[j]-mu)*rs*w[c] + bias[c]); }
}

// ---------------- generic bf16 copy of weights ---------------------------------------
__global__ __launch_bounds__(256) void cvt_bf(const float* __restrict__ src,
                                              unsigned short* __restrict__ dst, int n){
  int i = blockIdx.x*256 + threadIdx.x;
  if(i < n) dst[i] = f2bf(src[i]);
}

// ---------------- W_dt[dep][n][k] = sum_j dtw[dep][n][j] * xpw[dep][j][k] ------------
__global__ __launch_bounds__(256) void wdt_kernel(const float* __restrict__ dtw,
                                                  const float* __restrict__ xpw,
                                                  unsigned short* __restrict__ wdt){
  int idx = blockIdx.x*256 + threadIdx.x;   // 0..524287
  int dep = idx >> 18;
  int r = idx & 262143;
  int n = r >> 9, k = r & 511;
  const float* dw = dtw + (size_t)dep*512*16 + n*16;
  const float* xp = xpw + (size_t)dep*48*512 + k;
  float acc = 0.f;
  #pragma unroll
  for(int j=0;j<16;j++) acc += dw[j] * xp[(size_t)j*512];
  wdt[idx] = f2bf(acc);
}

// ---------------- small all-global bf16 MFMA GEMM (kept for x_proj, N=32) ------------
template<int FM,int FN,int WM,int WN,int EPI,int WF,int WB>
__global__ __launch_bounds__(WM*WN*64) void gemm_mfma(
    const unsigned short* __restrict__ A,
    const unsigned short* __restrict__ W,
    const float* __restrict__ bias,
    float* __restrict__ Cf,
    unsigned short* __restrict__ Cb,
    int M, int N, int K){
  int tid = threadIdx.x;
  int l = tid & 63, w = tid >> 6;
  int w_n = w % WN, w_m = w / WN;
  int lr = l & 15, lk = l >> 4;
  int nb = blockIdx.x * (WN*FN*16) + w_n*(FN*16);
  int mb = blockIdx.y * (WM*FM*16) + w_m*(FM*16);
  const unsigned short* ap[FN];
  const unsigned short* bp[FM];
  #pragma unroll
  for(int i=0;i<FN;i++) ap[i] = W + (size_t)(nb + i*16 + lr)*K + lk*8;
  #pragma unroll
  for(int i=0;i<FM;i++) bp[i] = A + (size_t)(mb + i*16 + lr)*K + lk*8;
  f32x4 acc[FN][FM] = {};
  for(int k0=0;k0<K;k0+=32){
    short8 av[FN], bv[FM];
    #pragma unroll
    for(int i=0;i<FN;i++) av[i] = *(const short8*)(ap[i]);
    #pragma unroll
    for(int i=0;i<FM;i++) bv[i] = *(const short8*)(bp[i]);
    #pragma unroll
    for(int i=0;i<FN;i++)
      #pragma unroll
      for(int j=0;j<FM;j++)
        acc[i][j] = __builtin_amdgcn_mfma_f32_16x16x32_bf16(av[i], bv[j], acc[i][j], 0,0,0);
    #pragma unroll
    for(int i=0;i<FN;i++) ap[i] += 32;
    #pragma unroll
    for(int i=0;i<FM;i++) bp[i] += 32;
  }
  #pragma unroll
  for(int i=0;i<FN;i++){
    #pragma unroll
    for(int j=0;j<FM;j++){
      int m = mb + j*16 + lr;
      #pragma unroll
      for(int r=0;r<4;r++){
        int n = nb + i*16 + 4*lk + r;
        float v = acc[i][j][r];
        if(EPI==1) v = sp_f(v + bias[n]);
        if(WF) Cf[(size_t)m*N + n] = v;
        if(WB) Cb[(size_t)m*N + n] = f2bf(v);
      }
    }
  }
}

// ---------------- LDS-staged bf16 MFMA GEMM (proven R14): D[n][m] = W·A --------------
template<int EPI,int WF,int WB>
__global__ __launch_bounds__(256) void gemm_lds(
    const unsigned short* __restrict__ A,   // M x K (m rows, B-operand)
    const unsigned short* __restrict__ W,   // N x K (n rows, A-operand)
    const float* __restrict__ bias,
    float* __restrict__ Cf,
    unsigned short* __restrict__ Cb,
    int M, int N, int K){
  __shared__ unsigned short Wt[64][72];
  __shared__ unsigned short Xt[128][72];
  int tid = threadIdx.x;
  int l = tid & 63, w = tid >> 6;
  int lr = l & 15, lk = l >> 4;
  int w_n = w & 1, w_m = w >> 1;
  int nb = blockIdx.x * 64;
  int mb = blockIdx.y * 128;
  int srow = tid >> 3, sc8 = tid & 7;       // staging: 8 threads/row, 16B each
  f32x4 acc[2][4] = {};
  for(int k0 = 0; k0 < K; k0 += 64){
    __syncthreads();
    #pragma unroll
    for(int q=0;q<2;q++){
      int row = q*32 + srow;
      *(uint4*)&Wt[row][sc8*8] = *(const uint4*)(W + (size_t)(nb+row)*K + k0 + sc8*8);
    }
    #pragma unroll
    for(int q=0;q<4;q++){
      int row = q*32 + srow;
      *(uint4*)&Xt[row][sc8*8] = *(const uint4*)(A + (size_t)(mb+row)*K + k0 + sc8*8);
    }
    __syncthreads();
    #pragma unroll
    for(int kk=0;kk<2;kk++){
      short8 af[2], bf[4];
      #pragma unroll
      for(int i=0;i<2;i++) af[i] = *(const short8*)&Wt[w_n*32+i*16+lr][kk*32+lk*8];
      #pragma unroll
      for(int j=0;j<4;j++) bf[j] = *(const short8*)&Xt[w_m*64+j*16+lr][kk*32+lk*8];
      #pragma unroll
      for(int i=0;i<2;i++)
        #pragma unroll
        for(int j=0;j<4;j++)
          acc[i][j] = __builtin_amdgcn_mfma_f32_16x16x32_bf16(af[i], bf[j], acc[i][j], 0,0,0);
    }
  }
  #pragma unroll
  for(int i=0;i<2;i++){
    #pragma unroll
    for(int j=0;j<4;j++){
      int m = mb + w_m*64 + j*16 + lr;
      #pragma unroll
      for(int r=0;r<4;r++){
        int n = nb + w_n*32 + i*16 + 4*lk + r;
        float v = acc[i][j][r];
        if(EPI==1) v = sp_f(v + bias[n]);
        if(WF) Cf[(size_t)m*N + n] = v;
        if(WB) Cb[(size_t)m*N + n] = f2bf(v);
      }
    }
  }
}

// ---------------- causal depthwise conv1d (k=4) + bias + SiLU (xz bf16) -> u_bf -----
__global__ __launch_bounds__(256) void conv1d_silu_kernel(const unsigned short* __restrict__ xz,
                                                          const float* __restrict__ cw,
                                                          const float* __restrict__ cb,
                                                          unsigned short* __restrict__ ub){
  int g = blockIdx.x*256 + threadIdx.x;   // b*2^21 + l*512 + d
  int d = g & 511;
  int l = (g>>9) & 4095;
  int b = g >> 21;
  const unsigned short* up = xz + (size_t)b*LSEQ*1024 + d;
  float accv = cb[d];
  #pragma unroll
  for(int k=0;k<4;k++){
    int ls = l-3+k;
    float vv = (ls>=0) ? bf2f(up[(size_t)ls*1024]) : 0.f;
    accv += vv * cw[d*4+k];
  }
  ub[(size_t)g] = f2bf(silu_f(accv));
}

// ================= chunked selective scan (dt,u bf16; xdbl fp32 [B|C] 32/row) =======
__global__ __launch_bounds__(256) void scan_pass1(const unsigned short* __restrict__ dt,
                                                  const unsigned short* __restrict__ u,
                                                  const float* __restrict__ xdbl,
                                                  const float* __restrict__ A_log,
                                                  float* __restrict__ Ap,
                                                  float* __restrict__ Ep){
  int G = blockIdx.x*256 + threadIdx.x;
  int s  = G & 15;
  int dl = (G>>4)&3;
  int c  = (G>>6)&63;
  int dh = (G>>12)&127;
  int b  = G>>19;
  int d  = dh*4 + dl;
  float a = -__expf(A_log[d*16+s]);
  const unsigned short* dtp = dt + (size_t)b*LSEQ*512 + d;
  const unsigned short* up  = u  + (size_t)b*LSEQ*512 + d;
  const float* xb  = xdbl + (size_t)b*LSEQ*32;
  int t0 = c*CHL;
  float aprod = 1.f, h = 0.f;
  for(int tt=0;tt<CHL;tt++){
    int t = t0+tt;
    float dtv = bf2f(dtp[(size_t)t*512]);
    float uv  = bf2f(up[(size_t)t*512]);
    float bv  = xb[t*32 + s];
    float dA  = __expf(dtv*a);
    h = dA*h + dtv*bv*uv;
    aprod *= dA;
  }
  int idx = b*8192 + d*16 + s;       // 0..16383
  Ap[(size_t)c*16384 + idx] = aprod;
  Ep[(size_t)c*16384 + idx] = h;
}

__global__ __launch_bounds__(256) void scan_pass2(const float* __restrict__ Ap,
                                                  float* __restrict__ Ep){
  int idx = blockIdx.x*256 + threadIdx.x;   // 0..16383
  float h = 0.f;
  for(int c=0;c<NCH;c++){
    float a = Ap[(size_t)c*16384 + idx];
    float e = Ep[(size_t)c*16384 + idx];
    Ep[(size_t)c*16384 + idx] = h;
    h = a*h + e;
  }
}

__global__ __launch_bounds__(256) void scan_pass3(const unsigned short* __restrict__ dt,
                                                  const unsigned short* __restrict__ u,
                                                  const unsigned short* __restrict__ xz,
                                                  const float* __restrict__ xdbl,
                                                  const float* __restrict__ A_log,
                                                  const float* __restrict__ Ep,
                                                  const float* __restrict__ Dsk,
                                                  unsigned short* __restrict__ yb){
  int G = blockIdx.x*256 + threadIdx.x;
  int s  = G & 15;
  int dl = (G>>4)&3;
  int c  = (G>>6)&63;
  int dh = (G>>12)&127;
  int b  = G>>19;
  int d  = dh*4 + dl;
  float a = -__expf(A_log[d*16+s]);
  const unsigned short* dtp = dt + (size_t)b*LSEQ*512 + d;
  const unsigned short* up  = u  + (size_t)b*LSEQ*512 + d;
  const float* xb  = xdbl + (size_t)b*LSEQ*32;
  unsigned short* yp = yb + (size_t)b*LSEQ*512 + d;
  int idx = b*8192 + d*16 + s;
  float h = Ep[(size_t)c*16384 + idx];
  float dskv = Dsk[d];
  int t0 = c*CHL;
  for(int tt=0;tt<CHL;tt++){
    int t = t0+tt;
    float dtv = bf2f(dtp[(size_t)t*512]);
    float uv  = bf2f(up[(size_t)t*512]);
    float bv  = xb[t*32 + s];
    float cv  = xb[t*32 + 16 + s];
    float dA  = __expf(dtv*a);
    h = dA*h + dtv*bv*uv;
    float pp = h*cv;
    pp += __shfl_xor(pp,1);
    pp += __shfl_xor(pp,2);
    pp += __shfl_xor(pp,4);
    pp += __shfl_xor(pp,8);
    if(s==0){
      float z = bf2f(xz[(size_t)(b*LSEQ + t)*1024 + 512 + d]);
      yp[(size_t)t*512] = f2bf((pp + uv*dskv) * silu_f(z));
    }
  }
}

// ================= conv3d via double-buffered LDS MFMA implicit GEMM ================
// single-writer padded fill: every byte of xt written exactly once per call.
__global__ __launch_bounds__(256) void xt_fill(const float* __restrict__ x,
                                               unsigned short* __restrict__ xt){
  int bid = blockIdx.x;
  int b = bid / 324; int r = bid - b*324;
  int zz = r / 18, yy = r - zz*18;
  bool inner = (zz>=1 && zz<=16 && yy>=1 && yy<=16);
  unsigned short* xd = xt + (size_t)((b*18 + zz)*18 + yy)*18*256;
  const float* xs = x + (size_t)b*256*4096 + (zz-1)*256 + (yy-1)*16;
  int t = threadIdx.x;
  for(int u = t; u < 576; u += 256){
    int xpos = u >> 5;           // 0..17
    int ci0 = (u & 31) * 8;
    uint4 val = make_uint4(0,0,0,0);
    if(inner && xpos>=1 && xpos<=16){
      int xi = xpos-1;
      unsigned pk[4];
      #pragma unroll
      for(int j=0;j<4;j++){
        unsigned short lo = f2bf(xs[(size_t)(ci0+2*j  )*4096 + xi]);
        unsigned short hi = f2bf(xs[(size_t)(ci0+2*j+1)*4096 + xi]);
        pk[j] = (unsigned)lo | ((unsigned)hi << 16);
      }
      val = make_uint4(pk[0],pk[1],pk[2],pk[3]);
    }
    *(uint4*)(xd + (size_t)u*8) = val;
  }
}

__global__ __launch_bounds__(256) void wt_conv(const float* __restrict__ w3,
                                               unsigned short* __restrict__ wt){
  int idx = blockIdx.x*256 + threadIdx.x;   // 0..1,769,471
  int ci = idx & 255; int r = idx >> 8;     // 0..6911
  int tap = r % 27, co = r / 27;
  wt[idx] = f2bf(w3[(size_t)co*6912 + ci*27 + tap]);
}

// 256 blocks x 512 thr; 8 waves = 2(co-32) x 4(m-32). BM=128, BN=64, BK=128 (half-tap).
// Double-buffered LDS: per step {issue next-chunk global->reg loads, 16 MFMA on cur,
// ds_write regs to buf^1, ONE barrier}. 54 steps. Padded 272B rows: 2-way LDS alias
// (free). XCD-bijective swizzle for L2 locality (256%8==0).
__global__ __launch_bounds__(512) void conv3d_dbuf(const unsigned short* __restrict__ xt,
                                                   const unsigned short* __restrict__ wt,
                                                   const unsigned short* __restrict__ hb,
                                                   const float* __restrict__ prelu_a,
                                                   const float* __restrict__ scale,
                                                   float* __restrict__ out){
  __shared__ unsigned short Wt2[2][64][136];
  __shared__ unsigned short Xt2[2][128][136];
  int bid0 = blockIdx.x;
  int bid = (bid0 & 7)*32 + (bid0 >> 3);    // bijective XCD swizzle
  int nb = (bid & 3)*64;                    // co tile
  int mb = (bid >> 2)*128;                  // m tile
  int tid = threadIdx.x;
  int l = tid & 63, w = tid >> 6;
  int lr = l & 15, lk = l >> 4;
  int w_n = w & 1, w_m = w >> 1;            // 2 x 4
  int srow = tid >> 4, sch = tid & 15;      // staging: row-base 0..31, 16B chunk 0..15
  // X staging bases (tap-0 padded offsets) for the 4 row-chunks
  size_t xbase[4];
  #pragma unroll
  for(int q=0;q<4;q++){
    int m = mb + q*32 + srow;
    int b = m >> 12, sp = m & 4095;
    int z = sp >> 8, y = (sp >> 4) & 15, x = sp & 15;
    xbase[q] = (size_t)(((b*18 + z+1)*18 + (y+1))*18 + (x+1))*256 + sch*8;
  }
  const unsigned short* wrow0 = wt + (size_t)(nb + srow)*6912 + sch*8;
  const unsigned short* wrow1 = wt + (size_t)(nb + 32 + srow)*6912 + sch*8;

  // prologue: stage step 0 into buf 0 (tap 0, half 0)
  {
    int toff = (-324 - 18 - 1)*256;
    uint4 w0 = *(const uint4*)(wrow0);
    uint4 w1 = *(const uint4*)(wrow1);
    uint4 x0 = *(const uint4*)(xt + xbase[0] + toff);
    uint4 x1 = *(const uint4*)(xt + xbase[1] + toff);
    uint4 x2 = *(const uint4*)(xt + xbase[2] + toff);
    uint4 x3 = *(const uint4*)(xt + xbase[3] + toff);
    *(uint4*)&Wt2[0][srow   ][sch*8] = w0;
    *(uint4*)&Wt2[0][srow+32][sch*8] = w1;
    *(uint4*)&Xt2[0][srow    ][sch*8] = x0;
    *(uint4*)&Xt2[0][srow+32 ][sch*8] = x1;
    *(uint4*)&Xt2[0][srow+64 ][sch*8] = x2;
    *(uint4*)&Xt2[0][srow+96 ][sch*8] = x3;
  }
  __syncthreads();

  f32x4 acc[2][2] = {};
  int cur = 0;
  for(int s=0; s<54; ++s){
    uint4 wv0, wv1, xv0, xv1, xv2, xv3;
    if(s < 53){
      int sn = s+1;
      int tap = sn >> 1, h = sn & 1;
      int gz = tap/9; int rm = tap - gz*9; int gy = rm/3, gx = rm - gy*3;
      int toff = ((gz-1)*324 + (gy-1)*18 + (gx-1))*256 + h*128;
      int kco = tap*256 + h*128;
      wv0 = *(const uint4*)(wrow0 + kco);
      wv1 = *(const uint4*)(wrow1 + kco);
      xv0 = *(const uint4*)(xt + xbase[0] + toff);
      xv1 = *(const uint4*)(xt + xbase[1] + toff);
      xv2 = *(const uint4*)(xt + xbase[2] + toff);
      xv3 = *(const uint4*)(xt + xbase[3] + toff);
    }
    #pragma unroll
    for(int kk=0;kk<4;kk++){
      short8 af[2], bf[2];
      #pragma unroll
      for(int i=0;i<2;i++) af[i] = *(const short8*)&Wt2[cur][w_n*32+i*16+lr][kk*32+lk*8];
      #pragma unroll
      for(int j=0;j<2;j++) bf[j] = *(const short8*)&Xt2[cur][w_m*32+j*16+lr][kk*32+lk*8];
      #pragma unroll
      for(int i=0;i<2;i++)
        #pragma unroll
        for(int j=0;j<2;j++)
          acc[i][j] = __builtin_amdgcn_mfma_f32_16x16x32_bf16(af[i], bf[j], acc[i][j], 0,0,0);
    }
    if(s < 53){
      int nbuf = cur ^ 1;
      *(uint4*)&Wt2[nbuf][srow   ][sch*8] = wv0;
      *(uint4*)&Wt2[nbuf][srow+32][sch*8] = wv1;
      *(uint4*)&Xt2[nbuf][srow    ][sch*8] = xv0;
      *(uint4*)&Xt2[nbuf][srow+32 ][sch*8] = xv1;
      *(uint4*)&Xt2[nbuf][srow+64 ][sch*8] = xv2;
      *(uint4*)&Xt2[nbuf][srow+96 ][sch*8] = xv3;
      __syncthreads();
      cur = nbuf;
    }
  }

  float spv = sp_f(scale[0]);
  float pa = prelu_a[0];
  #pragma unroll
  for(int i=0;i<2;i++){
    #pragma unroll
    for(int j=0;j<2;j++){
      int m = mb + w_m*32 + j*16 + lr;
      int bb = m >> 12, sp = m & 4095;
      #pragma unroll
      for(int r=0;r<4;r++){
        int co = nb + w_n*32 + i*16 + 4*lk + r;
        float cval = acc[i][j][r];
        float pr = cval > 0.f ? cval : pa*cval;
        out[((size_t)(bb*256 + co))*4096 + sp] = bf2f(hb[(size_t)m*256 + co]) + spv*pr;
      }
    }
  }
}

extern "C" void kernel_launch(void* const* d_in, const int* in_sizes, int n_in,
                              void* d_out, int out_size, void* d_ws, size_t ws_size,
                              hipStream_t stream) {
  const float* x         = (const float*)d_in[0];
  const float* ln_w      = (const float*)d_in[1];
  const float* ln_b      = (const float*)d_in[2];
  const float* in_proj_w = (const float*)d_in[3];
  const float* conv_w    = (const float*)d_in[4];
  const float* conv_b    = (const float*)d_in[5];
  const float* x_proj_w  = (const float*)d_in[6];
  const float* dt_proj_w = (const float*)d_in[7];
  const float* dt_proj_b = (const float*)d_in[8];
  const float* A_log     = (const float*)d_in[9];
  const float* D_skip    = (const float*)d_in[10];
  const float* out_proj_w= (const float*)d_in[11];
  const float* conv3d_w  = (const float*)d_in[12];
  const float* prelu_a   = (const float*)d_in[13];
  const float* scale     = (const float*)d_in[14];
  float* out = (float*)d_out;

  // workspace layout (float offsets) — one producer per phase.
  float* ws   = (float*)d_ws;
  float* Ap   = ws;                               // 1,048,576 fl
  float* Ep   = Ap + 1048576;                     // 1,048,576 fl
  unsigned short* xz_bf = (unsigned short*)(Ep + 1048576);     // 8,388,608 bf16
  unsigned short* u_bf  = xz_bf + 8388608;        // 4,194,304 bf16
  float* xdbl = (float*)(u_bf + 4194304);         // 262,144 fl
  unsigned short* dt_bf = (unsigned short*)(xdbl + 262144);    // 4,194,304 bf16
  unsigned short* h_bf  = dt_bf + 4194304;        // 2,097,152 bf16 (LIVE at conv time)
  unsigned short* y_bf  = h_bf + 2097152;         // 4,194,304 bf16
  unsigned short* inw_bf   = y_bf + 4194304;      // 524,288 bf16
  unsigned short* ow_bf    = inw_bf + 524288;     // 262,144 bf16
  unsigned short* xpwbc_bf = ow_bf + 262144;      // 32,768 bf16
  unsigned short* wdt_bf   = xpwbc_bf + 32768;    // 524,288 bf16
  const size_t base_floats = 14565376;            // 58,261,504 bytes
  // xt/wt at dedicated tail (ws >= 77,070,336 B established by rounds 1-4 layouts)
  unsigned short* xt = (unsigned short*)(ws + base_floats);
  unsigned short* wt = xt + 2985984;

  // ---- weight prep (bf16) ----
  cvt_bf<<<2048, 256, 0, stream>>>(in_proj_w, inw_bf, 524288);
  cvt_bf<<<1024, 256, 0, stream>>>(out_proj_w, ow_bf, 262144);
  cvt_bf<<<64, 256, 0, stream>>>(x_proj_w + 16*512, xpwbc_bf, 16384);
  cvt_bf<<<64, 256, 0, stream>>>(x_proj_w + 48*512 + 16*512, xpwbc_bf + 16384, 16384);
  wdt_kernel<<<2048, 256, 0, stream>>>(dt_proj_w, x_proj_w, wdt_bf);

  ln_kernel<<<LSEQ*2, 64, 0, stream>>>(x, ln_w, ln_b, h_bf);

  for(int dep=0; dep<2; dep++){
    const unsigned short* inw = inw_bf   + (size_t)dep*262144;
    const unsigned short* oww = ow_bf    + (size_t)dep*131072;
    const unsigned short* xpw = xpwbc_bf + (size_t)dep*16384;
    const unsigned short* wdt = wdt_bf   + (size_t)dep*262144;
    const float* cw   = conv_w    + (size_t)dep*512*4;
    const float* cb   = conv_b    + (size_t)dep*512;
    const float* dtb  = dt_proj_b + (size_t)dep*512;
    const float* Alg  = A_log     + (size_t)dep*512*16;
    const float* Dsk  = D_skip    + (size_t)dep*512;

    // in_proj: xz_bf[8192,1024] = h_bf @ inw^T   (16 x 64 = 1024 blocks)
    gemm_lds<0,0,1><<<dim3(16,64), 256, 0, stream>>>(
        h_bf, inw, nullptr, nullptr, xz_bf, 8192, 1024, 256);
    conv1d_silu_kernel<<<16384, 256, 0, stream>>>(xz_bf, cw, cb, u_bf);
    // x_proj B,C: xdbl[8192,32] = u_bf @ xpw_bc^T  (256 blocks, all-global)
    gemm_mfma<1,1,2,2,0,1,0><<<dim3(1,256), 256, 0, stream>>>(
        u_bf, xpw, nullptr, xdbl, nullptr, 8192, 32, 512);
    // dt (folded): dt_bf[8192,512] = softplus(u_bf @ wdt^T + dtb)  (8 x 64 = 512 blocks)
    gemm_lds<1,0,1><<<dim3(8,64), 256, 0, stream>>>(
        u_bf, wdt, dtb, nullptr, dt_bf, 8192, 512, 512);

    scan_pass1<<<4096, 256, 0, stream>>>(dt_bf, u_bf, xdbl, Alg, Ap, Ep);
    scan_pass2<<<64, 256, 0, stream>>>(Ap, Ep);
    scan_pass3<<<4096, 256, 0, stream>>>(dt_bf, u_bf, xz_bf, xdbl, Alg, Ep, Dsk, y_bf);

    // out_proj: h_bf[8192,256] = y_bf @ ow^T  (4 x 64 = 256 blocks)
    gemm_lds<0,0,1><<<dim3(4,64), 256, 0, stream>>>(
        y_bf, oww, nullptr, nullptr, h_bf, 8192, 256, 512);
  }

  // conv3d: prep + double-buffered LDS MFMA conv with fused epilogue
  xt_fill<<<648, 256, 0, stream>>>(x, xt);
  wt_conv<<<6912, 256, 0, stream>>>(conv3d_w, wt);
  conv3d_dbuf<<<256, 512, 0, stream>>>(xt, wt, h_bf, prelu_a, scale, out);
}

// Round 16
// 382.366 us; speedup vs baseline: 1.8579x; 1.4194x over previous
//
#include <hip/hip_runtime.h>
#include <math.h>

#define LSEQ 4096
#define DIMC 256
#define DI   512
#define NCH  128    // chunks over L
#define CHL  32     // chunk length

typedef short short8 __attribute__((ext_vector_type(8)));
typedef float f32x4 __attribute__((ext_vector_type(4)));

__device__ __forceinline__ float sp_f(float v){ return fmaxf(v,0.f) + log1pf(__expf(-fabsf(v))); }
__device__ __forceinline__ float silu_f(float v){ return v/(1.f+__expf(-v)); }
__device__ __forceinline__ unsigned short f2bf(float f){
  unsigned u = __builtin_bit_cast(unsigned, f);
  unsigned r = (u + 0x7FFFu + ((u>>16)&1u)) >> 16;
  return (unsigned short)r;
}
__device__ __forceinline__ float bf2f(unsigned short us){
  unsigned u = ((unsigned)us)<<16;
  return __builtin_bit_cast(float, u);
}

// ---------------- LayerNorm: x (B,C,L) -> h_bf (B*L, C) bf16 -------------------------
__global__ __launch_bounds__(64) void ln_kernel(const float* __restrict__ x,
                                                const float* __restrict__ w,
                                                const float* __restrict__ bias,
                                                unsigned short* __restrict__ hb){
  int row = blockIdx.x;            // b*L + l
  int b = row >> 12, l = row & 4095;
  int i = threadIdx.x;             // 0..63
  const float* xb = x + (size_t)b*DIMC*LSEQ + l;
  float v[4]; float s=0.f, sq=0.f;
  #pragma unroll
  for(int j=0;j<4;j++){ float t = xb[(size_t)(j*64+i)*LSEQ]; v[j]=t; s+=t; sq+=t*t; }
  #pragma unroll
  for(int o=1;o<64;o<<=1){ s += __shfl_xor(s,o); sq += __shfl_xor(sq,o); }
  float mu = s*(1.f/256.f);
  float var = sq*(1.f/256.f) - mu*mu;
  float rs = rsqrtf(var + 1e-5f);
  unsigned short* hr = hb + (size_t)row*DIMC;
  #pragma unroll
  for(int j=0;j<4;j++){ int c=j*64+i; hr[c] = f2bf((v[j]-mu)*rs*w[c] + bias[c]); }
}

// ---------------- generic bf16 copy of weights ---------------------------------------
__global__ __launch_bounds__(256) void cvt_bf(const float* __restrict__ src,
                                              unsigned short* __restrict__ dst, int n){
  int i = blockIdx.x*256 + threadIdx.x;
  if(i < n) dst[i] = f2bf(src[i]);
}

// ---------------- W_dt[dep][n][k] = sum_j dtw[dep][n][j] * xpw[dep][j][k] ------------
__global__ __launch_bounds__(256) void wdt_kernel(const float* __restrict__ dtw,
                                                  const float* __restrict__ xpw,
                                                  unsigned short* __restrict__ wdt){
  int idx = blockIdx.x*256 + threadIdx.x;   // 0..524287
  int dep = idx >> 18;
  int r = idx & 262143;
  int n = r >> 9, k = r & 511;
  const float* dw = dtw + (size_t)dep*512*16 + n*16;
  const float* xp = xpw + (size_t)dep*48*512 + k;
  float acc = 0.f;
  #pragma unroll
  for(int j=0;j<16;j++) acc += dw[j] * xp[(size_t)j*512];
  wdt[idx] = f2bf(acc);
}

// ---------------- small all-global bf16 MFMA GEMM (kept for x_proj, N=32) ------------
template<int FM,int FN,int WM,int WN,int EPI,int WF,int WB>
__global__ __launch_bounds__(WM*WN*64) void gemm_mfma(
    const unsigned short* __restrict__ A,
    const unsigned short* __restrict__ W,
    const float* __restrict__ bias,
    float* __restrict__ Cf,
    unsigned short* __restrict__ Cb,
    int M, int N, int K){
  int tid = threadIdx.x;
  int l = tid & 63, w = tid >> 6;
  int w_n = w % WN, w_m = w / WN;
  int lr = l & 15, lk = l >> 4;
  int nb = blockIdx.x * (WN*FN*16) + w_n*(FN*16);
  int mb = blockIdx.y * (WM*FM*16) + w_m*(FM*16);
  const unsigned short* ap[FN];
  const unsigned short* bp[FM];
  #pragma unroll
  for(int i=0;i<FN;i++) ap[i] = W + (size_t)(nb + i*16 + lr)*K + lk*8;
  #pragma unroll
  for(int i=0;i<FM;i++) bp[i] = A + (size_t)(mb + i*16 + lr)*K + lk*8;
  f32x4 acc[FN][FM] = {};
  for(int k0=0;k0<K;k0+=32){
    short8 av[FN], bv[FM];
    #pragma unroll
    for(int i=0;i<FN;i++) av[i] = *(const short8*)(ap[i]);
    #pragma unroll
    for(int i=0;i<FM;i++) bv[i] = *(const short8*)(bp[i]);
    #pragma unroll
    for(int i=0;i<FN;i++)
      #pragma unroll
      for(int j=0;j<FM;j++)
        acc[i][j] = __builtin_amdgcn_mfma_f32_16x16x32_bf16(av[i], bv[j], acc[i][j], 0,0,0);
    #pragma unroll
    for(int i=0;i<FN;i++) ap[i] += 32;
    #pragma unroll
    for(int i=0;i<FM;i++) bp[i] += 32;
  }
  #pragma unroll
  for(int i=0;i<FN;i++){
    #pragma unroll
    for(int j=0;j<FM;j++){
      int m = mb + j*16 + lr;
      #pragma unroll
      for(int r=0;r<4;r++){
        int n = nb + i*16 + 4*lk + r;
        float v = acc[i][j][r];
        if(EPI==1) v = sp_f(v + bias[n]);
        if(WF) Cf[(size_t)m*N + n] = v;
        if(WB) Cb[(size_t)m*N + n] = f2bf(v);
      }
    }
  }
}

// ---------------- LDS-staged bf16 MFMA GEMM (proven R14): D[n][m] = W·A --------------
template<int EPI,int WF,int WB>
__global__ __launch_bounds__(256) void gemm_lds(
    const unsigned short* __restrict__ A,   // M x K (m rows, B-operand)
    const unsigned short* __restrict__ W,   // N x K (n rows, A-operand)
    const float* __restrict__ bias,
    float* __restrict__ Cf,
    unsigned short* __restrict__ Cb,
    int M, int N, int K){
  __shared__ unsigned short Wt[64][72];
  __shared__ unsigned short Xt[128][72];
  int tid = threadIdx.x;
  int l = tid & 63, w = tid >> 6;
  int lr = l & 15, lk = l >> 4;
  int w_n = w & 1, w_m = w >> 1;
  int nb = blockIdx.x * 64;
  int mb = blockIdx.y * 128;
  int srow = tid >> 3, sc8 = tid & 7;       // staging: 8 threads/row, 16B each
  f32x4 acc[2][4] = {};
  for(int k0 = 0; k0 < K; k0 += 64){
    __syncthreads();
    #pragma unroll
    for(int q=0;q<2;q++){
      int row = q*32 + srow;
      *(uint4*)&Wt[row][sc8*8] = *(const uint4*)(W + (size_t)(nb+row)*K + k0 + sc8*8);
    }
    #pragma unroll
    for(int q=0;q<4;q++){
      int row = q*32 + srow;
      *(uint4*)&Xt[row][sc8*8] = *(const uint4*)(A + (size_t)(mb+row)*K + k0 + sc8*8);
    }
    __syncthreads();
    #pragma unroll
    for(int kk=0;kk<2;kk++){
      short8 af[2], bf[4];
      #pragma unroll
      for(int i=0;i<2;i++) af[i] = *(const short8*)&Wt[w_n*32+i*16+lr][kk*32+lk*8];
      #pragma unroll
      for(int j=0;j<4;j++) bf[j] = *(const short8*)&Xt[w_m*64+j*16+lr][kk*32+lk*8];
      #pragma unroll
      for(int i=0;i<2;i++)
        #pragma unroll
        for(int j=0;j<4;j++)
          acc[i][j] = __builtin_amdgcn_mfma_f32_16x16x32_bf16(af[i], bf[j], acc[i][j], 0,0,0);
    }
  }
  #pragma unroll
  for(int i=0;i<2;i++){
    #pragma unroll
    for(int j=0;j<4;j++){
      int m = mb + w_m*64 + j*16 + lr;
      #pragma unroll
      for(int r=0;r<4;r++){
        int n = nb + w_n*32 + i*16 + 4*lk + r;
        float v = acc[i][j][r];
        if(EPI==1) v = sp_f(v + bias[n]);
        if(WF) Cf[(size_t)m*N + n] = v;
        if(WB) Cb[(size_t)m*N + n] = f2bf(v);
      }
    }
  }
}

// ---------------- causal depthwise conv1d (k=4) + bias + SiLU (xz bf16) -> u_bf -----
__global__ __launch_bounds__(256) void conv1d_silu_kernel(const unsigned short* __restrict__ xz,
                                                          const float* __restrict__ cw,
                                                          const float* __restrict__ cb,
                                                          unsigned short* __restrict__ ub){
  int g = blockIdx.x*256 + threadIdx.x;   // b*2^21 + l*512 + d
  int d = g & 511;
  int l = (g>>9) & 4095;
  int b = g >> 21;
  const unsigned short* up = xz + (size_t)b*LSEQ*1024 + d;
  float accv = cb[d];
  #pragma unroll
  for(int k=0;k<4;k++){
    int ls = l-3+k;
    float vv = (ls>=0) ? bf2f(up[(size_t)ls*1024]) : 0.f;
    accv += vv * cw[d*4+k];
  }
  ub[(size_t)g] = f2bf(silu_f(accv));
}

// ================= chunked selective scan, 16 states in registers ===================
// thread = (b, chunk, d). NCH=128 chunks of CHL=32. Ap/Ep slot layout: s*1024 + b*512+d
// (all stores/loads lane-coalesced). B/C chunk staged in LDS once per block.

__global__ __launch_bounds__(256) void scan_pass1(const unsigned short* __restrict__ dt,
                                                  const unsigned short* __restrict__ u,
                                                  const float* __restrict__ xdbl,
                                                  const float* __restrict__ A_log,
                                                  float* __restrict__ Ap,
                                                  float* __restrict__ Ep){
  __shared__ float bc[CHL*32];
  int bid = blockIdx.x;            // 512 = b(2) x ch(128) x dh(2)
  int b = bid >> 8, ch = (bid >> 1) & 127, dh = bid & 1;
  int tid = threadIdx.x;
  int d = dh*256 + tid;
  int row0 = b*4096 + ch*CHL;
  *(float4*)&bc[tid*4] = *(const float4*)&xdbl[(size_t)row0*32 + tid*4];
  __syncthreads();
  float a[16];
  #pragma unroll
  for(int s=0;s<16;s++) a[s] = -__expf(A_log[d*16+s]);
  float h[16];
  #pragma unroll
  for(int s=0;s<16;s++) h[s] = 0.f;
  float sumdt = 0.f;
  const unsigned short* dtp = dt + (size_t)row0*512 + d;
  const unsigned short* up  = u  + (size_t)row0*512 + d;
  for(int t=0;t<CHL;t++){
    float dtv = bf2f(dtp[(size_t)t*512]);
    float uv  = bf2f(up[(size_t)t*512]);
    float dtbu = dtv*uv;
    sumdt += dtv;
    #pragma unroll
    for(int s=0;s<16;s++){
      float dA = __expf(a[s]*dtv);
      h[s] = dA*h[s] + dtbu*bc[t*32+s];
    }
  }
  int bd = b*512 + d;
  #pragma unroll
  for(int s=0;s<16;s++){
    Ap[(size_t)ch*16384 + s*1024 + bd] = __expf(a[s]*sumdt);
    Ep[(size_t)ch*16384 + s*1024 + bd] = h[s];
  }
}

__global__ __launch_bounds__(256) void scan_pass2(const float* __restrict__ Ap,
                                                  float* __restrict__ Ep){
  int idx = blockIdx.x*256 + threadIdx.x;   // 0..16383
  float h = 0.f;
  for(int c=0;c<NCH;c++){
    float a = Ap[(size_t)c*16384 + idx];
    float e = Ep[(size_t)c*16384 + idx];
    Ep[(size_t)c*16384 + idx] = h;
    h = a*h + e;
  }
}

__global__ __launch_bounds__(256) void scan_pass3(const unsigned short* __restrict__ dt,
                                                  const unsigned short* __restrict__ u,
                                                  const unsigned short* __restrict__ xz,
                                                  const float* __restrict__ xdbl,
                                                  const float* __restrict__ A_log,
                                                  const float* __restrict__ Ep,
                                                  const float* __restrict__ Dsk,
                                                  unsigned short* __restrict__ yb){
  __shared__ float bc[CHL*32];
  int bid = blockIdx.x;            // 512 = b(2) x ch(128) x dh(2)
  int b = bid >> 8, ch = (bid >> 1) & 127, dh = bid & 1;
  int tid = threadIdx.x;
  int d = dh*256 + tid;
  int row0 = b*4096 + ch*CHL;
  *(float4*)&bc[tid*4] = *(const float4*)&xdbl[(size_t)row0*32 + tid*4];
  __syncthreads();
  float a[16];
  #pragma unroll
  for(int s=0;s<16;s++) a[s] = -__expf(A_log[d*16+s]);
  int bd = b*512 + d;
  float h[16];
  #pragma unroll
  for(int s=0;s<16;s++) h[s] = Ep[(size_t)ch*16384 + s*1024 + bd];
  float dskv = Dsk[d];
  const unsigned short* dtp = dt + (size_t)row0*512 + d;
  const unsigned short* up  = u  + (size_t)row0*512 + d;
  const unsigned short* zp  = xz + (size_t)row0*1024 + 512 + d;
  unsigned short* yp = yb + (size_t)row0*512 + d;
  for(int t=0;t<CHL;t++){
    float dtv = bf2f(dtp[(size_t)t*512]);
    float uv  = bf2f(up[(size_t)t*512]);
    float dtbu = dtv*uv;
    float y = 0.f;
    #pragma unroll
    for(int s=0;s<16;s++){
      float dA = __expf(a[s]*dtv);
      h[s] = dA*h[s] + dtbu*bc[t*32+s];
      y += h[s]*bc[t*32+16+s];
    }
    float z = bf2f(zp[(size_t)t*1024]);
    yp[(size_t)t*512] = f2bf((y + uv*dskv) * silu_f(z));
  }
}

// ================= conv3d via double-buffered LDS MFMA implicit GEMM ================
__global__ __launch_bounds__(256) void xt_fill(const float* __restrict__ x,
                                               unsigned short* __restrict__ xt){
  int bid = blockIdx.x;
  int b = bid / 324; int r = bid - b*324;
  int zz = r / 18, yy = r - zz*18;
  bool inner = (zz>=1 && zz<=16 && yy>=1 && yy<=16);
  unsigned short* xd = xt + (size_t)((b*18 + zz)*18 + yy)*18*256;
  const float* xs = x + (size_t)b*256*4096 + (zz-1)*256 + (yy-1)*16;
  int t = threadIdx.x;
  for(int u = t; u < 576; u += 256){
    int xpos = u >> 5;           // 0..17
    int ci0 = (u & 31) * 8;
    uint4 val = make_uint4(0,0,0,0);
    if(inner && xpos>=1 && xpos<=16){
      int xi = xpos-1;
      unsigned pk[4];
      #pragma unroll
      for(int j=0;j<4;j++){
        unsigned short lo = f2bf(xs[(size_t)(ci0+2*j  )*4096 + xi]);
        unsigned short hi = f2bf(xs[(size_t)(ci0+2*j+1)*4096 + xi]);
        pk[j] = (unsigned)lo | ((unsigned)hi << 16);
      }
      val = make_uint4(pk[0],pk[1],pk[2],pk[3]);
    }
    *(uint4*)(xd + (size_t)u*8) = val;
  }
}

__global__ __launch_bounds__(256) void wt_conv(const float* __restrict__ w3,
                                               unsigned short* __restrict__ wt){
  int idx = blockIdx.x*256 + threadIdx.x;   // 0..1,769,471
  int ci = idx & 255; int r = idx >> 8;     // 0..6911
  int tap = r % 27, co = r / 27;
  wt[idx] = f2bf(w3[(size_t)co*6912 + ci*27 + tap]);
}

__global__ __launch_bounds__(512) void conv3d_dbuf(const unsigned short* __restrict__ xt,
                                                   const unsigned short* __restrict__ wt,
                                                   const unsigned short* __restrict__ hb,
                                                   const float* __restrict__ prelu_a,
                                                   const float* __restrict__ scale,
                                                   float* __restrict__ out){
  __shared__ unsigned short Wt2[2][64][136];
  __shared__ unsigned short Xt2[2][128][136];
  int bid0 = blockIdx.x;
  int bid = (bid0 & 7)*32 + (bid0 >> 3);    // bijective XCD swizzle
  int nb = (bid & 3)*64;                    // co tile
  int mb = (bid >> 2)*128;                  // m tile
  int tid = threadIdx.x;
  int l = tid & 63, w = tid >> 6;
  int lr = l & 15, lk = l >> 4;
  int w_n = w & 1, w_m = w >> 1;            // 2 x 4
  int srow = tid >> 4, sch = tid & 15;      // staging: row-base 0..31, 16B chunk 0..15
  size_t xbase[4];
  #pragma unroll
  for(int q=0;q<4;q++){
    int m = mb + q*32 + srow;
    int b = m >> 12, sp = m & 4095;
    int z = sp >> 8, y = (sp >> 4) & 15, x = sp & 15;
    xbase[q] = (size_t)(((b*18 + z+1)*18 + (y+1))*18 + (x+1))*256 + sch*8;
  }
  const unsigned short* wrow0 = wt + (size_t)(nb + srow)*6912 + sch*8;
  const unsigned short* wrow1 = wt + (size_t)(nb + 32 + srow)*6912 + sch*8;

  {
    int toff = (-324 - 18 - 1)*256;
    uint4 w0 = *(const uint4*)(wrow0);
    uint4 w1 = *(const uint4*)(wrow1);
    uint4 x0 = *(const uint4*)(xt + xbase[0] + toff);
    uint4 x1 = *(const uint4*)(xt + xbase[1] + toff);
    uint4 x2 = *(const uint4*)(xt + xbase[2] + toff);
    uint4 x3 = *(const uint4*)(xt + xbase[3] + toff);
    *(uint4*)&Wt2[0][srow   ][sch*8] = w0;
    *(uint4*)&Wt2[0][srow+32][sch*8] = w1;
    *(uint4*)&Xt2[0][srow    ][sch*8] = x0;
    *(uint4*)&Xt2[0][srow+32 ][sch*8] = x1;
    *(uint4*)&Xt2[0][srow+64 ][sch*8] = x2;
    *(uint4*)&Xt2[0][srow+96 ][sch*8] = x3;
  }
  __syncthreads();

  f32x4 acc[2][2] = {};
  int cur = 0;
  for(int s=0; s<54; ++s){
    uint4 wv0, wv1, xv0, xv1, xv2, xv3;
    if(s < 53){
      int sn = s+1;
      int tap = sn >> 1, h = sn & 1;
      int gz = tap/9; int rm = tap - gz*9; int gy = rm/3, gx = rm - gy*3;
      int toff = ((gz-1)*324 + (gy-1)*18 + (gx-1))*256 + h*128;
      int kco = tap*256 + h*128;
      wv0 = *(const uint4*)(wrow0 + kco);
      wv1 = *(const uint4*)(wrow1 + kco);
      xv0 = *(const uint4*)(xt + xbase[0] + toff);
      xv1 = *(const uint4*)(xt + xbase[1] + toff);
      xv2 = *(const uint4*)(xt + xbase[2] + toff);
      xv3 = *(const uint4*)(xt + xbase[3] + toff);
    }
    #pragma unroll
    for(int kk=0;kk<4;kk++){
      short8 af[2], bf[2];
      #pragma unroll
      for(int i=0;i<2;i++) af[i] = *(const short8*)&Wt2[cur][w_n*32+i*16+lr][kk*32+lk*8];
      #pragma unroll
      for(int j=0;j<2;j++) bf[j] = *(const short8*)&Xt2[cur][w_m*32+j*16+lr][kk*32+lk*8];
      #pragma unroll
      for(int i=0;i<2;i++)
        #pragma unroll
        for(int j=0;j<2;j++)
          acc[i][j] = __builtin_amdgcn_mfma_f32_16x16x32_bf16(af[i], bf[j], acc[i][j], 0,0,0);
    }
    if(s < 53){
      int nbuf = cur ^ 1;
      *(uint4*)&Wt2[nbuf][srow   ][sch*8] = wv0;
      *(uint4*)&Wt2[nbuf][srow+32][sch*8] = wv1;
      *(uint4*)&Xt2[nbuf][srow    ][sch*8] = xv0;
      *(uint4*)&Xt2[nbuf][srow+32 ][sch*8] = xv1;
      *(uint4*)&Xt2[nbuf][srow+64 ][sch*8] = xv2;
      *(uint4*)&Xt2[nbuf][srow+96 ][sch*8] = xv3;
      __syncthreads();
      cur = nbuf;
    }
  }

  float spv = sp_f(scale[0]);
  float pa = prelu_a[0];
  #pragma unroll
  for(int i=0;i<2;i++){
    #pragma unroll
    for(int j=0;j<2;j++){
      int m = mb + w_m*32 + j*16 + lr;
      int bb = m >> 12, sp = m & 4095;
      #pragma unroll
      for(int r=0;r<4;r++){
        int co = nb + w_n*32 + i*16 + 4*lk + r;
        float cval = acc[i][j][r];
        float pr = cval > 0.f ? cval : pa*cval;
        out[((size_t)(bb*256 + co))*4096 + sp] = bf2f(hb[(size_t)m*256 + co]) + spv*pr;
      }
    }
  }
}

extern "C" void kernel_launch(void* const* d_in, const int* in_sizes, int n_in,
                              void* d_out, int out_size, void* d_ws, size_t ws_size,
                              hipStream_t stream) {
  const float* x         = (const float*)d_in[0];
  const float* ln_w      = (const float*)d_in[1];
  const float* ln_b      = (const float*)d_in[2];
  const float* in_proj_w = (const float*)d_in[3];
  const float* conv_w    = (const float*)d_in[4];
  const float* conv_b    = (const float*)d_in[5];
  const float* x_proj_w  = (const float*)d_in[6];
  const float* dt_proj_w = (const float*)d_in[7];
  const float* dt_proj_b = (const float*)d_in[8];
  const float* A_log     = (const float*)d_in[9];
  const float* D_skip    = (const float*)d_in[10];
  const float* out_proj_w= (const float*)d_in[11];
  const float* conv3d_w  = (const float*)d_in[12];
  const float* prelu_a   = (const float*)d_in[13];
  const float* scale     = (const float*)d_in[14];
  float* out = (float*)d_out;

  // workspace layout (float offsets) — one producer per phase.
  float* ws   = (float*)d_ws;
  float* Ap   = ws;                               // 2,097,152 fl (NCH=128 planes)
  float* Ep   = Ap + 2097152;                     // 2,097,152 fl
  unsigned short* xz_bf = (unsigned short*)(Ep + 2097152);     // 8,388,608 bf16
  unsigned short* u_bf  = xz_bf + 8388608;        // 4,194,304 bf16
  float* xdbl = (float*)(u_bf + 4194304);         // 262,144 fl
  unsigned short* dt_bf = (unsigned short*)(xdbl + 262144);    // 4,194,304 bf16
  unsigned short* h_bf  = dt_bf + 4194304;        // 2,097,152 bf16 (LIVE at conv time)
  unsigned short* y_bf  = h_bf + 2097152;         // 4,194,304 bf16
  unsigned short* inw_bf   = y_bf + 4194304;      // 524,288 bf16
  unsigned short* ow_bf    = inw_bf + 524288;     // 262,144 bf16
  unsigned short* xpwbc_bf = ow_bf + 262144;      // 32,768 bf16
  unsigned short* wdt_bf   = xpwbc_bf + 32768;    // 524,288 bf16
  const size_t base_floats = 16662528;            // 66,650,112 bytes
  // xt/wt tail: end = 76,161,024 B <= 77,070,336 B (proven in R2's layout)
  unsigned short* xt = (unsigned short*)(ws + base_floats);
  unsigned short* wt = xt + 2985984;

  // ---- weight prep (bf16) ----
  cvt_bf<<<2048, 256, 0, stream>>>(in_proj_w, inw_bf, 524288);
  cvt_bf<<<1024, 256, 0, stream>>>(out_proj_w, ow_bf, 262144);
  cvt_bf<<<64, 256, 0, stream>>>(x_proj_w + 16*512, xpwbc_bf, 16384);
  cvt_bf<<<64, 256, 0, stream>>>(x_proj_w + 48*512 + 16*512, xpwbc_bf + 16384, 16384);
  wdt_kernel<<<2048, 256, 0, stream>>>(dt_proj_w, x_proj_w, wdt_bf);

  ln_kernel<<<LSEQ*2, 64, 0, stream>>>(x, ln_w, ln_b, h_bf);

  for(int dep=0; dep<2; dep++){
    const unsigned short* inw = inw_bf   + (size_t)dep*262144;
    const unsigned short* oww = ow_bf    + (size_t)dep*131072;
    const unsigned short* xpw = xpwbc_bf + (size_t)dep*16384;
    const unsigned short* wdt = wdt_bf   + (size_t)dep*262144;
    const float* cw   = conv_w    + (size_t)dep*512*4;
    const float* cb   = conv_b    + (size_t)dep*512;
    const float* dtb  = dt_proj_b + (size_t)dep*512;
    const float* Alg  = A_log     + (size_t)dep*512*16;
    const float* Dsk  = D_skip    + (size_t)dep*512;

    // in_proj: xz_bf[8192,1024] = h_bf @ inw^T   (16 x 64 = 1024 blocks)
    gemm_lds<0,0,1><<<dim3(16,64), 256, 0, stream>>>(
        h_bf, inw, nullptr, nullptr, xz_bf, 8192, 1024, 256);
    conv1d_silu_kernel<<<16384, 256, 0, stream>>>(xz_bf, cw, cb, u_bf);
    // x_proj B,C: xdbl[8192,32] = u_bf @ xpw_bc^T  (256 blocks, all-global)
    gemm_mfma<1,1,2,2,0,1,0><<<dim3(1,256), 256, 0, stream>>>(
        u_bf, xpw, nullptr, xdbl, nullptr, 8192, 32, 512);
    // dt (folded): dt_bf[8192,512] = softplus(u_bf @ wdt^T + dtb)  (8 x 64 = 512 blocks)
    gemm_lds<1,0,1><<<dim3(8,64), 256, 0, stream>>>(
        u_bf, wdt, dtb, nullptr, dt_bf, 8192, 512, 512);

    scan_pass1<<<512, 256, 0, stream>>>(dt_bf, u_bf, xdbl, Alg, Ap, Ep);
    scan_pass2<<<64, 256, 0, stream>>>(Ap, Ep);
    scan_pass3<<<512, 256, 0, stream>>>(dt_bf, u_bf, xz_bf, xdbl, Alg, Ep, Dsk, y_bf);

    // out_proj: h_bf[8192,256] = y_bf @ ow^T  (4 x 64 = 256 blocks)
    gemm_lds<0,0,1><<<dim3(4,64), 256, 0, stream>>>(
        y_bf, oww, nullptr, nullptr, h_bf, 8192, 256, 512);
  }

  // conv3d: prep + double-buffered LDS MFMA conv with fused epilogue
  xt_fill<<<648, 256, 0, stream>>>(x, xt);
  wt_conv<<<6912, 256, 0, stream>>>(conv3d_w, wt);
  conv3d_dbuf<<<256, 512, 0, stream>>>(xt, wt, h_bf, prelu_a, scale, out);
}